// Round 5
// baseline (2706.708 us; speedup 1.0000x reference)
//
#include <hip/hip_runtime.h>
#include <hip/hip_fp16.h>
#include <cstdint>

#define EPSLN 1e-5f
#define NPB 512          // nodes per bucket (power of 2)
#define NPB_SHIFT 9
#define MAXB 512         // max buckets (N <= 262144)
#define TILE 16384       // edges per sort tile
#define SRC_BITS 18      // src id fits 18 bits (N <= 262144)
#define SRC_MASK 0x3FFFF

// ---------------------------------------------------------------------------
// Pass 1: per-bucket histogram of dst
// ---------------------------------------------------------------------------
__global__ __launch_bounds__(512) void k_hist(const int* __restrict__ dst,
                                              int* __restrict__ bcount, int E, int B) {
    __shared__ int hist[MAXB];
    for (int b = threadIdx.x; b < B; b += 512) hist[b] = 0;
    __syncthreads();
    int beg = blockIdx.x * TILE;
    int end = min(beg + TILE, E);
    for (int i = beg + threadIdx.x; i < end; i += 512)
        atomicAdd(&hist[__builtin_nontemporal_load(dst + i) >> NPB_SHIFT], 1);
    __syncthreads();
    for (int b = threadIdx.x; b < B; b += 512)
        if (hist[b]) atomicAdd(&bcount[b], hist[b]);
}

// ---------------------------------------------------------------------------
// Pass 2: scan bucket counts -> boff / bcur
// ---------------------------------------------------------------------------
__global__ __launch_bounds__(512) void k_bscan(const int* __restrict__ bcount,
                                               int* __restrict__ boff,
                                               int* __restrict__ bcur,
                                               int B, int E) {
    __shared__ int sm[512];
    int v = (threadIdx.x < B) ? bcount[threadIdx.x] : 0;
    sm[threadIdx.x] = v;
    __syncthreads();
    for (int off = 1; off < 512; off <<= 1) {
        int t = (threadIdx.x >= off) ? sm[threadIdx.x - off] : 0;
        __syncthreads();
        sm[threadIdx.x] += t;
        __syncthreads();
    }
    if (threadIdx.x < B) {
        int e = sm[threadIdx.x] - v;
        boff[threadIdx.x] = e;
        bcur[threadIdx.x] = e;
    }
    if (threadIdx.x == 0) boff[B] = E;
}

// ---------------------------------------------------------------------------
// Pass 3: tiled bucket scatter. Packed word = (dst_local << 18) | src.
// ---------------------------------------------------------------------------
__global__ __launch_bounds__(512) void k_scatter(const int* __restrict__ src,
                                                 const int* __restrict__ dst,
                                                 int* __restrict__ bcur,
                                                 unsigned* __restrict__ packed,
                                                 int E, int B) {
    __shared__ int hist[MAXB];
    __shared__ int base[MAXB];
    for (int b = threadIdx.x; b < B; b += 512) hist[b] = 0;
    __syncthreads();
    int beg = blockIdx.x * TILE;
    int end = min(beg + TILE, E);
    for (int i = beg + threadIdx.x; i < end; i += 512)
        atomicAdd(&hist[dst[i] >> NPB_SHIFT], 1);
    __syncthreads();
    for (int b = threadIdx.x; b < B; b += 512) {
        int c = hist[b];
        base[b] = c ? atomicAdd(&bcur[b], c) : 0;
        hist[b] = 0;
    }
    __syncthreads();
    for (int i = beg + threadIdx.x; i < end; i += 512) {
        int d = dst[i];
        int s = src[i];
        int bkt = d >> NPB_SHIFT;
        int pos = base[bkt] + atomicAdd(&hist[bkt], 1);
        packed[pos] = ((unsigned)(d & (NPB - 1)) << SRC_BITS) | (unsigned)s;
    }
}

// ---------------------------------------------------------------------------
// Pass 4: per-bucket degree histogram -> dinv / sqd / prescaled xs3
// ---------------------------------------------------------------------------
__global__ __launch_bounds__(512) void k_deg2(const int* __restrict__ boff,
                                              const unsigned* __restrict__ packed,
                                              float* __restrict__ dinv,
                                              float* __restrict__ sqd,
                                              const float* __restrict__ node,
                                              float* __restrict__ xs3,   // [N,4]
                                              int N) {
    __shared__ int hist[NPB];
    int b = blockIdx.x;
    int beg = boff[b], end = boff[b + 1];
    int tid = threadIdx.x;
    hist[tid] = 0;
    __syncthreads();
    for (int i = beg + tid; i < end; i += 512)
        atomicAdd(&hist[packed[i] >> SRC_BITS], 1);
    __syncthreads();
    int v = b * NPB + tid;
    if (v < N) {
        float c = (float)(hist[tid] + 1);   // +1: self-loop
        float di = rsqrtf(c);
        dinv[v] = di;
        sqd[v] = sqrtf(c);                  // = 1/di, residual reconstruction
        xs3[(size_t)v * 4 + 0] = di * node[(size_t)v * 3 + 0];
        xs3[(size_t)v * 4 + 1] = di * node[(size_t)v * 3 + 1];
        xs3[(size_t)v * 4 + 2] = di * node[(size_t)v * 3 + 2];
        xs3[(size_t)v * 4 + 3] = 0.f;
    }
}

// ---------------------------------------------------------------------------
// Fused bucket conv: LDS plane accumulation + per-node dense/LN/res/relu/FC.
// MODE 0: first conv (F=3, fp32 gathers from xs3) -> xsout/xhout
// MODE 1: mid layer (fp16 gathers)                -> xsout/xhout
// MODE 2: final layer                              -> @Wfc+bfc -> out
// ---------------------------------------------------------------------------
template <int MODE>
__global__ __launch_bounds__(512) void k_bconv(const int* __restrict__ boff,
                                               const unsigned* __restrict__ packed,
                                               const float* __restrict__ dinv,
                                               const float* __restrict__ sqd,
                                               const float* __restrict__ xs,   // fp32: MODE0 [N,4], else [N,8]
                                               const __half* __restrict__ xsh, // fp16 [N,8] (MODE1/2)
                                               const float* __restrict__ W,
                                               const float* __restrict__ b,
                                               const float* __restrict__ gamma,
                                               const float* __restrict__ beta,
                                               const float* __restrict__ Wfc,
                                               const float* __restrict__ bfc,
                                               float* __restrict__ xsout,      // fp32 [N,8]
                                               __half* __restrict__ xhout,     // fp16 [N,8]
                                               float* __restrict__ outfc,      // [N,3]
                                               int N) {
    constexpr int F = (MODE == 0) ? 3 : 6;
    __shared__ float acc[F * NPB];   // feature-plane layout: acc[f*NPB + dl]
    int bkt = blockIdx.x;
    int beg = boff[bkt], end = boff[bkt + 1];
    int tid = threadIdx.x;
    for (int i = tid; i < F * NPB; i += 512) acc[i] = 0.f;
    __syncthreads();

    if constexpr (MODE == 0) {
        const float4* x4 = (const float4*)xs;
        for (int i = beg + tid; i < end; i += 512) {
            unsigned w = packed[i];
            int s = (int)(w & SRC_MASK);
            int dl = (int)(w >> SRC_BITS);
            float4 p = x4[s];
            atomicAdd(&acc[0 * NPB + dl], p.x);
            atomicAdd(&acc[1 * NPB + dl], p.y);
            atomicAdd(&acc[2 * NPB + dl], p.z);
        }
    } else {
        const float4* xh4 = (const float4*)xsh;   // 8 halves = 16B
        for (int i = beg + tid; i < end; i += 512) {
            unsigned w = packed[i];
            int s = (int)(w & SRC_MASK);
            int dl = (int)(w >> SRC_BITS);
            float4 raw = xh4[s];
            const __half2* h2 = (const __half2*)&raw;
            float2 p0 = __half22float2(h2[0]);
            float2 p1 = __half22float2(h2[1]);
            float2 p2 = __half22float2(h2[2]);
            atomicAdd(&acc[0 * NPB + dl], p0.x);
            atomicAdd(&acc[1 * NPB + dl], p0.y);
            atomicAdd(&acc[2 * NPB + dl], p1.x);
            atomicAdd(&acc[3 * NPB + dl], p1.y);
            atomicAdd(&acc[4 * NPB + dl], p2.x);
            atomicAdd(&acc[5 * NPB + dl], p2.y);
        }
    }
    __syncthreads();

    int v = bkt * NPB + tid;
    if (v >= N) return;
    float di = dinv[v];

    float t[F];
    if constexpr (MODE == 0) {
        const float* xr = xs + (size_t)v * 4;
#pragma unroll
        for (int f = 0; f < 3; ++f) t[f] = di * (acc[f * NPB + tid] + xr[f]);
    } else {
        const float* xr = xs + (size_t)v * 8;
#pragma unroll
        for (int f = 0; f < 6; ++f) t[f] = di * (acc[f * NPB + tid] + xr[f]);
    }

    float y[6];
#pragma unroll
    for (int j = 0; j < 6; ++j) {
        float a = b[j];
#pragma unroll
        for (int k = 0; k < F; ++k) a += t[k] * W[k * 6 + j];
        y[j] = a;
    }

    if constexpr (MODE == 0) {
        float* o = xsout + (size_t)v * 8;
        *(float4*)o = make_float4(di * y[0], di * y[1], di * y[2], di * y[3]);
        *(float2*)(o + 4) = make_float2(di * y[4], di * y[5]);
        __half2* oh = (__half2*)(xhout + (size_t)v * 8);
        oh[0] = __floats2half2_rn(di * y[0], di * y[1]);
        oh[1] = __floats2half2_rn(di * y[2], di * y[3]);
        oh[2] = __floats2half2_rn(di * y[4], di * y[5]);
        oh[3] = __floats2half2_rn(0.f, 0.f);
    } else {
        float mu = 0.f;
#pragma unroll
        for (int j = 0; j < 6; ++j) mu += y[j];
        mu *= (1.f / 6.f);
        float var = 0.f;
#pragma unroll
        for (int j = 0; j < 6; ++j) { float dl = y[j] - mu; var += dl * dl; }
        var *= (1.f / 6.f);
        float rs = rsqrtf(var + EPSLN);
        float sq = sqd[v];
        const float* xr = xs + (size_t)v * 8;   // residual = xs * sqrt(deg+1)
        float r[6];
#pragma unroll
        for (int j = 0; j < 6; ++j) {
            float z = (y[j] - mu) * rs * gamma[j] + beta[j] + xr[j] * sq;
            r[j] = z > 0.f ? z : 0.f;
        }
        if constexpr (MODE == 1) {
            float* o = xsout + (size_t)v * 8;
            *(float4*)o = make_float4(di * r[0], di * r[1], di * r[2], di * r[3]);
            *(float2*)(o + 4) = make_float2(di * r[4], di * r[5]);
            __half2* oh = (__half2*)(xhout + (size_t)v * 8);
            oh[0] = __floats2half2_rn(di * r[0], di * r[1]);
            oh[1] = __floats2half2_rn(di * r[2], di * r[3]);
            oh[2] = __floats2half2_rn(di * r[4], di * r[5]);
            oh[3] = __floats2half2_rn(0.f, 0.f);
        } else {
#pragma unroll
            for (int j = 0; j < 3; ++j) {
                float a = bfc[j];
#pragma unroll
                for (int k = 0; k < 6; ++k) a += r[k] * Wfc[k * 3 + j];
                outfc[(size_t)v * 3 + j] = a;
            }
        }
    }
}

// ---------------------------------------------------------------------------
extern "C" void kernel_launch(void* const* d_in, const int* in_sizes, int n_in,
                              void* d_out, int out_size, void* d_ws, size_t ws_size,
                              hipStream_t stream) {
    const float* node  = (const float*)d_in[0];
    const int*   edges = (const int*)d_in[1];
    const float* W1    = (const float*)d_in[2];
    const float* b1    = (const float*)d_in[3];
    const float* Wl    = (const float*)d_in[4];
    const float* bl    = (const float*)d_in[5];
    const float* gamma = (const float*)d_in[6];
    const float* beta  = (const float*)d_in[7];
    const float* Wfc   = (const float*)d_in[8];
    const float* bfc   = (const float*)d_in[9];
    float* out = (float*)d_out;

    const int N     = in_sizes[0] / 3;
    const int E     = in_sizes[1] / 2;
    const int STEPS = in_sizes[4] / 36;
    const int* src = edges;
    const int* dst = edges + E;
    const int B = (N + NPB - 1) / NPB;   // 391 for N=200000

    char* ws = (char*)d_ws;
    size_t off = 0;
    auto alloc = [&](size_t bytes) -> void* {
        void* p = ws + off;
        off += (bytes + 255) & ~(size_t)255;
        return p;
    };
    int*      bcount = (int*)alloc((size_t)B * sizeof(int));
    int*      boff   = (int*)alloc((size_t)(B + 1) * sizeof(int));
    int*      bcur   = (int*)alloc((size_t)B * sizeof(int));
    float*    dinv   = (float*)alloc((size_t)N * sizeof(float));
    float*    sqd    = (float*)alloc((size_t)N * sizeof(float));
    unsigned* packed = (unsigned*)alloc((size_t)E * sizeof(unsigned));
    float*    xs3    = (float*)alloc((size_t)N * 4 * sizeof(float));
    float*    xsa    = (float*)alloc((size_t)N * 8 * sizeof(float));
    float*    xsb    = (float*)alloc((size_t)N * 8 * sizeof(float));
    __half*   xha    = (__half*)alloc((size_t)N * 8 * sizeof(__half));
    __half*   xhb    = (__half*)alloc((size_t)N * 8 * sizeof(__half));
    (void)ws_size;

    const int gS = (E + TILE - 1) / TILE;

    hipMemsetAsync(bcount, 0, (size_t)B * sizeof(int), stream);
    k_hist<<<gS, 512, 0, stream>>>(dst, bcount, E, B);
    k_bscan<<<1, 512, 0, stream>>>(bcount, boff, bcur, B, E);
    k_scatter<<<gS, 512, 0, stream>>>(src, dst, bcur, packed, E, B);
    k_deg2<<<B, 512, 0, stream>>>(boff, packed, dinv, sqd, node, xs3, N);

    // Conv 1 (F=3): xsa/xha = dinv * ((A_hat @ node) @ W1 + b1)
    k_bconv<0><<<B, 512, 0, stream>>>(boff, packed, dinv, sqd, xs3, nullptr,
                                      W1, b1, nullptr, nullptr, nullptr, nullptr,
                                      xsa, xha, nullptr, N);

    float* xscur = xsa;   __half* xhcur = xha;
    float* xsnxt = xsb;   __half* xhnxt = xhb;
    for (int i = 0; i < STEPS; ++i) {
        const float* W  = Wl + (size_t)i * 36;
        const float* bb = bl + (size_t)i * 6;
        const float* g  = gamma + (size_t)i * 6;
        const float* be = beta + (size_t)i * 6;
        if (i == STEPS - 1) {
            k_bconv<2><<<B, 512, 0, stream>>>(boff, packed, dinv, sqd, xscur, xhcur,
                                              W, bb, g, be, Wfc, bfc,
                                              nullptr, nullptr, out, N);
        } else {
            k_bconv<1><<<B, 512, 0, stream>>>(boff, packed, dinv, sqd, xscur, xhcur,
                                              W, bb, g, be, nullptr, nullptr,
                                              xsnxt, xhnxt, nullptr, N);
        }
        float* t1 = xscur; xscur = xsnxt; xsnxt = t1;
        __half* t2 = xhcur; xhcur = xhnxt; xhnxt = t2;
    }
}

// Round 6
// 1057.699 us; speedup vs baseline: 2.5591x; 2.5591x over previous
//
#include <hip/hip_runtime.h>
#include <hip/hip_fp16.h>
#include <cstdint>

#define EPSLN 1e-5f
#define NPB 512          // nodes per bucket (power of 2)
#define NPB_SHIFT 9
#define MAXB 512         // max buckets (N <= 262144)
#define TILE 32768       // edges per sort tile
#define SRC_BITS 18      // src id fits 18 bits (N <= 262144)
#define SRC_MASK 0x3FFFF

// ---------------------------------------------------------------------------
// Pass 1: per-bucket histogram of dst
// ---------------------------------------------------------------------------
__global__ __launch_bounds__(512) void k_hist(const int* __restrict__ dst,
                                              int* __restrict__ bcount, int E, int B) {
    __shared__ int hist[MAXB];
    if (threadIdx.x < B) hist[threadIdx.x] = 0;
    __syncthreads();
    int beg = blockIdx.x * TILE;
    int end = min(beg + TILE, E);
    for (int i = beg + threadIdx.x; i < end; i += 512)
        atomicAdd(&hist[__builtin_nontemporal_load(dst + i) >> NPB_SHIFT], 1);
    __syncthreads();
    if (threadIdx.x < B && hist[threadIdx.x])
        atomicAdd(&bcount[threadIdx.x], hist[threadIdx.x]);
}

// ---------------------------------------------------------------------------
// Pass 2: scan bucket counts -> boff / bcur; seed ptr[N]=E
// ---------------------------------------------------------------------------
__global__ __launch_bounds__(512) void k_bscan(const int* __restrict__ bcount,
                                               int* __restrict__ boff,
                                               int* __restrict__ bcur,
                                               int* __restrict__ ptr,
                                               int B, int N, int E) {
    __shared__ int sm[512];
    int v = (threadIdx.x < B) ? bcount[threadIdx.x] : 0;
    sm[threadIdx.x] = v;
    __syncthreads();
    for (int off = 1; off < 512; off <<= 1) {
        int t = (threadIdx.x >= off) ? sm[threadIdx.x - off] : 0;
        __syncthreads();
        sm[threadIdx.x] += t;
        __syncthreads();
    }
    if (threadIdx.x < B) {
        int e = sm[threadIdx.x] - v;
        boff[threadIdx.x] = e;
        bcur[threadIdx.x] = e;
    }
    if (threadIdx.x == 0) { boff[B] = E; ptr[N] = E; }
}

// ---------------------------------------------------------------------------
// Pass 3: tiled bucket scatter. Packed word = (dst_local << 18) | src.
// 391 buckets x ~84 edges per tile -> ~336B contiguous chunks per bucket.
// ---------------------------------------------------------------------------
__global__ __launch_bounds__(512) void k_scatter(const int* __restrict__ src,
                                                 const int* __restrict__ dst,
                                                 int* __restrict__ bcur,
                                                 unsigned* __restrict__ packed,
                                                 int E, int B) {
    __shared__ int hist[MAXB];
    __shared__ int base[MAXB];
    if (threadIdx.x < B) hist[threadIdx.x] = 0;
    __syncthreads();
    int beg = blockIdx.x * TILE;
    int end = min(beg + TILE, E);
    for (int i = beg + threadIdx.x; i < end; i += 512)
        atomicAdd(&hist[dst[i] >> NPB_SHIFT], 1);
    __syncthreads();
    if (threadIdx.x < B) {
        int c = hist[threadIdx.x];
        base[threadIdx.x] = c ? atomicAdd(&bcur[threadIdx.x], c) : 0;
        hist[threadIdx.x] = 0;
    }
    __syncthreads();
    for (int i = beg + threadIdx.x; i < end; i += 512) {
        int d = dst[i];
        int s = src[i];
        int bkt = d >> NPB_SHIFT;
        int pos = base[bkt] + atomicAdd(&hist[bkt], 1);
        packed[pos] = ((unsigned)(d & (NPB - 1)) << SRC_BITS) | (unsigned)s;
    }
}

// ---------------------------------------------------------------------------
// Pass 4: per-bucket fine sort (two-pass, writes stay in the block's private
// 128KB csr region) + fused degree/dinv/ptr/xs3 production.
// ---------------------------------------------------------------------------
__global__ __launch_bounds__(512) void k_fine(const int* __restrict__ boff,
                                              const unsigned* __restrict__ packed,
                                              int* __restrict__ csr,
                                              int* __restrict__ ptr,
                                              float* __restrict__ dinv,
                                              float* __restrict__ sqd,
                                              const float* __restrict__ node,
                                              float* __restrict__ xs3,   // [N,4]
                                              int N) {
    __shared__ int hist[NPB];
    __shared__ int cur[NPB];
    int b = blockIdx.x;
    int beg = boff[b], end = boff[b + 1];
    int tid = threadIdx.x;
    hist[tid] = 0;
    __syncthreads();
    for (int i = beg + tid; i < end; i += 512)
        atomicAdd(&hist[packed[i] >> SRC_BITS], 1);
    __syncthreads();
    int hv = hist[tid];
    cur[tid] = hv;
    __syncthreads();
    for (int off = 1; off < NPB; off <<= 1) {
        int t = (tid >= off) ? cur[tid - off] : 0;
        __syncthreads();
        cur[tid] += t;
        __syncthreads();
    }
    int ex = cur[tid] - hv;  // exclusive
    int v = b * NPB + tid;
    if (v < N) {
        ptr[v] = beg + ex;
        float c = (float)(hv + 1);      // +1: self-loop
        float di = rsqrtf(c);
        dinv[v] = di;
        sqd[v] = sqrtf(c);              // = 1/di, residual reconstruction
        xs3[(size_t)v * 4 + 0] = di * node[(size_t)v * 3 + 0];
        xs3[(size_t)v * 4 + 1] = di * node[(size_t)v * 3 + 1];
        xs3[(size_t)v * 4 + 2] = di * node[(size_t)v * 3 + 2];
        xs3[(size_t)v * 4 + 3] = 0.f;
    }
    cur[tid] = ex;  // placement cursor
    __syncthreads();
    for (int i = beg + tid; i < end; i += 512) {
        unsigned w = packed[i];
        int dl = (int)(w >> SRC_BITS);
        int pos = atomicAdd(&cur[dl], 1);
        csr[beg + pos] = (int)(w & SRC_MASK);
    }
}

// ---------------------------------------------------------------------------
// Fused conv (round-4 proven): wave-per-node gather + shuffle reduce +
// per-node dense/LN/res/relu/FC. Gathers fp16 rows (16B); self-loop +
// residual from fp32 copy.
// MODE 0: first conv (F=3, fp32 gathers). MODE 1: mid. MODE 2: final -> out.
// ---------------------------------------------------------------------------
template <int MODE>
__global__ __launch_bounds__(256) void k_conv(const int* __restrict__ ptr,
                                              const int* __restrict__ csr,
                                              const float* __restrict__ dinv,
                                              const float* __restrict__ sqd,
                                              const float* __restrict__ xs,   // fp32: MODE0 [N,4], else [N,8]
                                              const __half* __restrict__ xsh, // fp16 [N,8] (MODE1/2)
                                              const float* __restrict__ W,
                                              const float* __restrict__ b,
                                              const float* __restrict__ gamma,
                                              const float* __restrict__ beta,
                                              const float* __restrict__ Wfc,
                                              const float* __restrict__ bfc,
                                              float* __restrict__ xsout,      // fp32 [N,8]
                                              __half* __restrict__ xhout,     // fp16 [N,8]
                                              float* __restrict__ outfc,      // [N,3]
                                              int N) {
    constexpr int F = (MODE == 0) ? 3 : 6;
    int wave = threadIdx.x >> 6;
    int lane = threadIdx.x & 63;
    int v = blockIdx.x * 4 + wave;
    if (v >= N) return;
    int beg = ptr[v], end = ptr[v + 1];

    float a0 = 0.f, a1 = 0.f, a2 = 0.f, a3 = 0.f, a4 = 0.f, a5 = 0.f;
    if constexpr (F == 3) {
        const float4* x4 = (const float4*)xs;
        for (int i = beg + lane; i < end; i += 64) {
            float4 p = x4[__builtin_nontemporal_load(csr + i)];
            a0 += p.x; a1 += p.y; a2 += p.z;
        }
        if (lane == 0) { float4 p = x4[v]; a0 += p.x; a1 += p.y; a2 += p.z; }
    } else {
        const float4* xh4 = (const float4*)xsh;  // 8 halves = 16B
        for (int i = beg + lane; i < end; i += 64) {
            float4 raw = xh4[__builtin_nontemporal_load(csr + i)];
            const __half2* h2 = (const __half2*)&raw;
            float2 p0 = __half22float2(h2[0]);
            float2 p1 = __half22float2(h2[1]);
            float2 p2 = __half22float2(h2[2]);
            a0 += p0.x; a1 += p0.y; a2 += p1.x; a3 += p1.y; a4 += p2.x; a5 += p2.y;
        }
        if (lane == 0) {  // self-loop, fp32
            const float* r = xs + (size_t)v * 8;
            float4 p = *(const float4*)r;
            float2 q = *(const float2*)(r + 4);
            a0 += p.x; a1 += p.y; a2 += p.z; a3 += p.w; a4 += q.x; a5 += q.y;
        }
    }
#pragma unroll
    for (int off = 32; off >= 1; off >>= 1) {
        a0 += __shfl_down(a0, off);
        a1 += __shfl_down(a1, off);
        a2 += __shfl_down(a2, off);
        if constexpr (F == 6) {
            a3 += __shfl_down(a3, off);
            a4 += __shfl_down(a4, off);
            a5 += __shfl_down(a5, off);
        }
    }
    if (lane != 0) return;

    float di = dinv[v];
    float t[F];
    t[0] = di * a0; t[1] = di * a1; t[2] = di * a2;
    if constexpr (F == 6) { t[3] = di * a3; t[4] = di * a4; t[5] = di * a5; }

    float y[6];
#pragma unroll
    for (int j = 0; j < 6; ++j) {
        float acc = b[j];
#pragma unroll
        for (int k = 0; k < F; ++k) acc += t[k] * W[k * 6 + j];
        y[j] = acc;
    }

    if constexpr (MODE == 0) {
        float* o = xsout + (size_t)v * 8;
        *(float4*)o = make_float4(di * y[0], di * y[1], di * y[2], di * y[3]);
        *(float2*)(o + 4) = make_float2(di * y[4], di * y[5]);
        __half2* oh = (__half2*)(xhout + (size_t)v * 8);
        oh[0] = __floats2half2_rn(di * y[0], di * y[1]);
        oh[1] = __floats2half2_rn(di * y[2], di * y[3]);
        oh[2] = __floats2half2_rn(di * y[4], di * y[5]);
        oh[3] = __floats2half2_rn(0.f, 0.f);
    } else {
        float mu = 0.f;
#pragma unroll
        for (int j = 0; j < 6; ++j) mu += y[j];
        mu *= (1.f / 6.f);
        float var = 0.f;
#pragma unroll
        for (int j = 0; j < 6; ++j) { float dl = y[j] - mu; var += dl * dl; }
        var *= (1.f / 6.f);
        float rs = rsqrtf(var + EPSLN);
        float sq = sqd[v];
        const float* xr = xs + (size_t)v * 8;   // residual = xs * sqrt(deg+1)
        float r[6];
#pragma unroll
        for (int j = 0; j < 6; ++j) {
            float z = (y[j] - mu) * rs * gamma[j] + beta[j] + xr[j] * sq;
            r[j] = z > 0.f ? z : 0.f;
        }
        if constexpr (MODE == 1) {
            float* o = xsout + (size_t)v * 8;
            *(float4*)o = make_float4(di * r[0], di * r[1], di * r[2], di * r[3]);
            *(float2*)(o + 4) = make_float2(di * r[4], di * r[5]);
            __half2* oh = (__half2*)(xhout + (size_t)v * 8);
            oh[0] = __floats2half2_rn(di * r[0], di * r[1]);
            oh[1] = __floats2half2_rn(di * r[2], di * r[3]);
            oh[2] = __floats2half2_rn(di * r[4], di * r[5]);
            oh[3] = __floats2half2_rn(0.f, 0.f);
        } else {
#pragma unroll
            for (int j = 0; j < 3; ++j) {
                float acc = bfc[j];
#pragma unroll
                for (int k = 0; k < 6; ++k) acc += r[k] * Wfc[k * 3 + j];
                outfc[(size_t)v * 3 + j] = acc;
            }
        }
    }
}

// ---------------------------------------------------------------------------
extern "C" void kernel_launch(void* const* d_in, const int* in_sizes, int n_in,
                              void* d_out, int out_size, void* d_ws, size_t ws_size,
                              hipStream_t stream) {
    const float* node  = (const float*)d_in[0];
    const int*   edges = (const int*)d_in[1];
    const float* W1    = (const float*)d_in[2];
    const float* b1    = (const float*)d_in[3];
    const float* Wl    = (const float*)d_in[4];
    const float* bl    = (const float*)d_in[5];
    const float* gamma = (const float*)d_in[6];
    const float* beta  = (const float*)d_in[7];
    const float* Wfc   = (const float*)d_in[8];
    const float* bfc   = (const float*)d_in[9];
    float* out = (float*)d_out;

    const int N     = in_sizes[0] / 3;
    const int E     = in_sizes[1] / 2;
    const int STEPS = in_sizes[4] / 36;
    const int* src = edges;
    const int* dst = edges + E;
    const int B = (N + NPB - 1) / NPB;   // 391 for N=200000

    char* ws = (char*)d_ws;
    size_t off = 0;
    auto alloc = [&](size_t bytes) -> void* {
        void* p = ws + off;
        off += (bytes + 255) & ~(size_t)255;
        return p;
    };
    int*      bcount = (int*)alloc((size_t)B * sizeof(int));
    int*      boff   = (int*)alloc((size_t)(B + 1) * sizeof(int));
    int*      bcur   = (int*)alloc((size_t)B * sizeof(int));
    int*      ptr    = (int*)alloc((size_t)(N + 1) * sizeof(int));
    float*    dinv   = (float*)alloc((size_t)N * sizeof(float));
    float*    sqd    = (float*)alloc((size_t)N * sizeof(float));
    unsigned* packed = (unsigned*)alloc((size_t)E * sizeof(unsigned));
    int*      csr    = (int*)alloc((size_t)E * sizeof(int));
    float*    xs3    = (float*)alloc((size_t)N * 4 * sizeof(float));
    float*    xsa    = (float*)alloc((size_t)N * 8 * sizeof(float));
    float*    xsb    = (float*)alloc((size_t)N * 8 * sizeof(float));
    __half*   xha    = (__half*)alloc((size_t)N * 8 * sizeof(__half));
    __half*   xhb    = (__half*)alloc((size_t)N * 8 * sizeof(__half));
    (void)ws_size;

    const int gS = (E + TILE - 1) / TILE;   // 391
    const int gC = (N + 3) / 4;

    hipMemsetAsync(bcount, 0, (size_t)B * sizeof(int), stream);
    k_hist<<<gS, 512, 0, stream>>>(dst, bcount, E, B);
    k_bscan<<<1, 512, 0, stream>>>(bcount, boff, bcur, ptr, B, N, E);
    k_scatter<<<gS, 512, 0, stream>>>(src, dst, bcur, packed, E, B);
    k_fine<<<B, 512, 0, stream>>>(boff, packed, csr, ptr, dinv, sqd, node, xs3, N);

    // Conv 1 (F=3): xsa/xha = dinv * ((A_hat @ node) @ W1 + b1)
    k_conv<0><<<gC, 256, 0, stream>>>(ptr, csr, dinv, sqd, xs3, nullptr, W1, b1,
                                      nullptr, nullptr, nullptr, nullptr,
                                      xsa, xha, nullptr, N);

    float* xscur = xsa;   __half* xhcur = xha;
    float* xsnxt = xsb;   __half* xhnxt = xhb;
    for (int i = 0; i < STEPS; ++i) {
        const float* W  = Wl + (size_t)i * 36;
        const float* bb = bl + (size_t)i * 6;
        const float* g  = gamma + (size_t)i * 6;
        const float* be = beta + (size_t)i * 6;
        if (i == STEPS - 1) {
            k_conv<2><<<gC, 256, 0, stream>>>(ptr, csr, dinv, sqd, xscur, xhcur, W, bb,
                                              g, be, Wfc, bfc, nullptr, nullptr, out, N);
        } else {
            k_conv<1><<<gC, 256, 0, stream>>>(ptr, csr, dinv, sqd, xscur, xhcur, W, bb,
                                              g, be, nullptr, nullptr, xsnxt, xhnxt, nullptr, N);
        }
        float* t1 = xscur; xscur = xsnxt; xsnxt = t1;
        __half* t2 = xhcur; xhcur = xhnxt; xhnxt = t2;
    }
}

// Round 7
// 951.630 us; speedup vs baseline: 2.8443x; 1.1115x over previous
//
#include <hip/hip_runtime.h>
#include <hip/hip_fp16.h>
#include <cstdint>

#define EPSLN 1e-5f
#define NPB 512          // nodes per bucket (power of 2)
#define NPB_SHIFT 9
#define MAXB 512         // max buckets (N <= 262144)
#define TILE 16384       // edges per sort tile (LDS staging = 64KB)
#define SRC_BITS 18      // src id fits 18 bits (N <= 262144)
#define SRC_MASK 0x3FFFF

// ---------------------------------------------------------------------------
// Pass 1: per-bucket histogram of dst (int4-vectorized stream)
// ---------------------------------------------------------------------------
__global__ __launch_bounds__(512) void k_hist(const int* __restrict__ dst,
                                              int* __restrict__ bcount, int E, int B) {
    __shared__ int hist[MAXB];
    if (threadIdx.x < B) hist[threadIdx.x] = 0;
    __syncthreads();
    int beg = blockIdx.x * TILE;
    int end = min(beg + TILE, E);
    if (end - beg == TILE) {
        const int4* d4 = (const int4*)(dst + beg);
#pragma unroll
        for (int k = 0; k < TILE / 512 / 4; ++k) {
            int4 q = d4[threadIdx.x + k * 512];
            atomicAdd(&hist[q.x >> NPB_SHIFT], 1);
            atomicAdd(&hist[q.y >> NPB_SHIFT], 1);
            atomicAdd(&hist[q.z >> NPB_SHIFT], 1);
            atomicAdd(&hist[q.w >> NPB_SHIFT], 1);
        }
    } else {
        for (int i = beg + threadIdx.x; i < end; i += 512)
            atomicAdd(&hist[dst[i] >> NPB_SHIFT], 1);
    }
    __syncthreads();
    if (threadIdx.x < B && hist[threadIdx.x])
        atomicAdd(&bcount[threadIdx.x], hist[threadIdx.x]);
}

// ---------------------------------------------------------------------------
// Pass 2: scan bucket counts -> boff / bcur; seed ptr[N]=E
// ---------------------------------------------------------------------------
__global__ __launch_bounds__(512) void k_bscan(const int* __restrict__ bcount,
                                               int* __restrict__ boff,
                                               int* __restrict__ bcur,
                                               int* __restrict__ ptr,
                                               int B, int N, int E) {
    __shared__ int sm[512];
    int v = (threadIdx.x < B) ? bcount[threadIdx.x] : 0;
    sm[threadIdx.x] = v;
    __syncthreads();
    for (int off = 1; off < 512; off <<= 1) {
        int t = (threadIdx.x >= off) ? sm[threadIdx.x - off] : 0;
        __syncthreads();
        sm[threadIdx.x] += t;
        __syncthreads();
    }
    if (threadIdx.x < B) {
        int e = sm[threadIdx.x] - v;
        boff[threadIdx.x] = e;
        bcur[threadIdx.x] = e;
    }
    if (threadIdx.x == 0) { boff[B] = E; ptr[N] = E; }
}

// ---------------------------------------------------------------------------
// Pass 3: LDS-staged bucket scatter. Tile is sorted by bucket in LDS, then
// drained linearly so every bucket chunk is one coalesced global burst
// (L2 merges full lines -> write amp ~1.2x instead of ~4x).
// ---------------------------------------------------------------------------
__global__ __launch_bounds__(512) void k_scatter(const int* __restrict__ src,
                                                 const int* __restrict__ dst,
                                                 int* __restrict__ bcur,
                                                 unsigned* __restrict__ packed,
                                                 int E, int B) {
    __shared__ unsigned stg[TILE];     // 64 KB staging
    __shared__ int hist[MAXB];         // per-bucket count, then placement cursor
    __shared__ int lbase[MAXB + 1];    // exclusive scan (local segment bases)
    __shared__ int gbase[MAXB];        // reserved global chunk base
    __shared__ int sm[512];
    int tid = threadIdx.x;
    if (tid < B) hist[tid] = 0;
    __syncthreads();

    int beg = blockIdx.x * TILE;
    int end = min(beg + TILE, E);
    int cnt = end - beg;

    // Phase A: histogram (dst stream; stays hot in L2 for phase C re-read)
    for (int i = beg + tid; i < end; i += 512)
        atomicAdd(&hist[dst[i] >> NPB_SHIFT], 1);
    __syncthreads();

    // Phase B: local scan + global reservation
    int v = (tid < B) ? hist[tid] : 0;
    sm[tid] = v;
    __syncthreads();
    for (int off = 1; off < 512; off <<= 1) {
        int t = (tid >= off) ? sm[tid - off] : 0;
        __syncthreads();
        sm[tid] += t;
        __syncthreads();
    }
    if (tid < B) {
        lbase[tid] = sm[tid] - v;
        gbase[tid] = v ? atomicAdd(&bcur[tid], v) : 0;
        hist[tid] = 0;  // becomes placement cursor
    }
    if (tid == 0) lbase[B] = cnt;
    __syncthreads();

    // Phase C: place packed words into staging, sorted by bucket
    for (int i = beg + tid; i < end; i += 512) {
        int d = dst[i];
        int s = src[i];
        int bkt = d >> NPB_SHIFT;
        int pos = lbase[bkt] + atomicAdd(&hist[bkt], 1);
        stg[pos] = ((unsigned)(d & (NPB - 1)) << SRC_BITS) | (unsigned)s;
    }
    __syncthreads();

    // Phase D: linear drain; bucket via binary search (adjacent j -> same
    // bucket -> LDS broadcast). Consecutive threads hit consecutive global
    // addresses within each chunk -> coalesced full-line bursts.
    for (int j = tid; j < cnt; j += 512) {
        int lo = 0, hi = B;
        while (hi - lo > 1) {
            int mid = (lo + hi) >> 1;
            if (lbase[mid] <= j) lo = mid; else hi = mid;
        }
        packed[gbase[lo] + (j - lbase[lo])] = stg[j];
    }
}

// ---------------------------------------------------------------------------
// Pass 4: per-bucket fine sort (two-pass, block-private 128KB csr region) +
// fused degree/dinv/ptr/xs3 production.
// ---------------------------------------------------------------------------
__global__ __launch_bounds__(512) void k_fine(const int* __restrict__ boff,
                                              const unsigned* __restrict__ packed,
                                              int* __restrict__ csr,
                                              int* __restrict__ ptr,
                                              float* __restrict__ dinv,
                                              float* __restrict__ sqd,
                                              const float* __restrict__ node,
                                              float* __restrict__ xs3,   // [N,4]
                                              int N) {
    __shared__ int hist[NPB];
    __shared__ int cur[NPB];
    int b = blockIdx.x;
    int beg = boff[b], end = boff[b + 1];
    int tid = threadIdx.x;
    hist[tid] = 0;
    __syncthreads();
    for (int i = beg + tid; i < end; i += 512)
        atomicAdd(&hist[packed[i] >> SRC_BITS], 1);
    __syncthreads();
    int hv = hist[tid];
    cur[tid] = hv;
    __syncthreads();
    for (int off = 1; off < NPB; off <<= 1) {
        int t = (tid >= off) ? cur[tid - off] : 0;
        __syncthreads();
        cur[tid] += t;
        __syncthreads();
    }
    int ex = cur[tid] - hv;  // exclusive
    int v = b * NPB + tid;
    if (v < N) {
        ptr[v] = beg + ex;
        float c = (float)(hv + 1);      // +1: self-loop
        float di = rsqrtf(c);
        dinv[v] = di;
        sqd[v] = sqrtf(c);              // = 1/di, residual reconstruction
        xs3[(size_t)v * 4 + 0] = di * node[(size_t)v * 3 + 0];
        xs3[(size_t)v * 4 + 1] = di * node[(size_t)v * 3 + 1];
        xs3[(size_t)v * 4 + 2] = di * node[(size_t)v * 3 + 2];
        xs3[(size_t)v * 4 + 3] = 0.f;
    }
    cur[tid] = ex;  // placement cursor
    __syncthreads();
    for (int i = beg + tid; i < end; i += 512) {
        unsigned w = packed[i];
        int dl = (int)(w >> SRC_BITS);
        int pos = atomicAdd(&cur[dl], 1);
        csr[beg + pos] = (int)(w & SRC_MASK);
    }
}

// ---------------------------------------------------------------------------
// Fused conv: wave-per-node gather + shuffle reduce + per-node dense/LN/
// res/relu/FC. Gathers fp16 rows (16B); self-loop + residual from fp32 copy.
// MODE 0: first conv (F=3, fp32 gathers). MODE 1: mid. MODE 2: final -> out.
// ---------------------------------------------------------------------------
template <int MODE>
__global__ __launch_bounds__(256) void k_conv(const int* __restrict__ ptr,
                                              const int* __restrict__ csr,
                                              const float* __restrict__ dinv,
                                              const float* __restrict__ sqd,
                                              const float* __restrict__ xs,   // fp32: MODE0 [N,4], else [N,8]
                                              const __half* __restrict__ xsh, // fp16 [N,8] (MODE1/2)
                                              const float* __restrict__ W,
                                              const float* __restrict__ b,
                                              const float* __restrict__ gamma,
                                              const float* __restrict__ beta,
                                              const float* __restrict__ Wfc,
                                              const float* __restrict__ bfc,
                                              float* __restrict__ xsout,      // fp32 [N,8]
                                              __half* __restrict__ xhout,     // fp16 [N,8]
                                              float* __restrict__ outfc,      // [N,3]
                                              int N) {
    constexpr int F = (MODE == 0) ? 3 : 6;
    int wave = threadIdx.x >> 6;
    int lane = threadIdx.x & 63;
    int v = blockIdx.x * 4 + wave;
    if (v >= N) return;
    int beg = ptr[v], end = ptr[v + 1];

    float a0 = 0.f, a1 = 0.f, a2 = 0.f, a3 = 0.f, a4 = 0.f, a5 = 0.f;
    if constexpr (F == 3) {
        const float4* x4 = (const float4*)xs;
        for (int i = beg + lane; i < end; i += 64) {
            float4 p = x4[__builtin_nontemporal_load(csr + i)];
            a0 += p.x; a1 += p.y; a2 += p.z;
        }
        if (lane == 0) { float4 p = x4[v]; a0 += p.x; a1 += p.y; a2 += p.z; }
    } else {
        const float4* xh4 = (const float4*)xsh;  // 8 halves = 16B
        for (int i = beg + lane; i < end; i += 64) {
            float4 raw = xh4[__builtin_nontemporal_load(csr + i)];
            const __half2* h2 = (const __half2*)&raw;
            float2 p0 = __half22float2(h2[0]);
            float2 p1 = __half22float2(h2[1]);
            float2 p2 = __half22float2(h2[2]);
            a0 += p0.x; a1 += p0.y; a2 += p1.x; a3 += p1.y; a4 += p2.x; a5 += p2.y;
        }
        if (lane == 0) {  // self-loop, fp32
            const float* r = xs + (size_t)v * 8;
            float4 p = *(const float4*)r;
            float2 q = *(const float2*)(r + 4);
            a0 += p.x; a1 += p.y; a2 += p.z; a3 += p.w; a4 += q.x; a5 += q.y;
        }
    }
#pragma unroll
    for (int off = 32; off >= 1; off >>= 1) {
        a0 += __shfl_down(a0, off);
        a1 += __shfl_down(a1, off);
        a2 += __shfl_down(a2, off);
        if constexpr (F == 6) {
            a3 += __shfl_down(a3, off);
            a4 += __shfl_down(a4, off);
            a5 += __shfl_down(a5, off);
        }
    }
    if (lane != 0) return;

    float di = dinv[v];
    float t[F];
    t[0] = di * a0; t[1] = di * a1; t[2] = di * a2;
    if constexpr (F == 6) { t[3] = di * a3; t[4] = di * a4; t[5] = di * a5; }

    float y[6];
#pragma unroll
    for (int j = 0; j < 6; ++j) {
        float acc = b[j];
#pragma unroll
        for (int k = 0; k < F; ++k) acc += t[k] * W[k * 6 + j];
        y[j] = acc;
    }

    if constexpr (MODE == 0) {
        float* o = xsout + (size_t)v * 8;
        *(float4*)o = make_float4(di * y[0], di * y[1], di * y[2], di * y[3]);
        *(float2*)(o + 4) = make_float2(di * y[4], di * y[5]);
        __half2* oh = (__half2*)(xhout + (size_t)v * 8);
        oh[0] = __floats2half2_rn(di * y[0], di * y[1]);
        oh[1] = __floats2half2_rn(di * y[2], di * y[3]);
        oh[2] = __floats2half2_rn(di * y[4], di * y[5]);
        oh[3] = __floats2half2_rn(0.f, 0.f);
    } else {
        float mu = 0.f;
#pragma unroll
        for (int j = 0; j < 6; ++j) mu += y[j];
        mu *= (1.f / 6.f);
        float var = 0.f;
#pragma unroll
        for (int j = 0; j < 6; ++j) { float dl = y[j] - mu; var += dl * dl; }
        var *= (1.f / 6.f);
        float rs = rsqrtf(var + EPSLN);
        float sq = sqd[v];
        const float* xr = xs + (size_t)v * 8;   // residual = xs * sqrt(deg+1)
        float r[6];
#pragma unroll
        for (int j = 0; j < 6; ++j) {
            float z = (y[j] - mu) * rs * gamma[j] + beta[j] + xr[j] * sq;
            r[j] = z > 0.f ? z : 0.f;
        }
        if constexpr (MODE == 1) {
            float* o = xsout + (size_t)v * 8;
            *(float4*)o = make_float4(di * r[0], di * r[1], di * r[2], di * r[3]);
            *(float2*)(o + 4) = make_float2(di * r[4], di * r[5]);
            __half2* oh = (__half2*)(xhout + (size_t)v * 8);
            oh[0] = __floats2half2_rn(di * r[0], di * r[1]);
            oh[1] = __floats2half2_rn(di * r[2], di * r[3]);
            oh[2] = __floats2half2_rn(di * r[4], di * r[5]);
            oh[3] = __floats2half2_rn(0.f, 0.f);
        } else {
#pragma unroll
            for (int j = 0; j < 3; ++j) {
                float acc = bfc[j];
#pragma unroll
                for (int k = 0; k < 6; ++k) acc += r[k] * Wfc[k * 3 + j];
                outfc[(size_t)v * 3 + j] = acc;
            }
        }
    }
}

// ---------------------------------------------------------------------------
extern "C" void kernel_launch(void* const* d_in, const int* in_sizes, int n_in,
                              void* d_out, int out_size, void* d_ws, size_t ws_size,
                              hipStream_t stream) {
    const float* node  = (const float*)d_in[0];
    const int*   edges = (const int*)d_in[1];
    const float* W1    = (const float*)d_in[2];
    const float* b1    = (const float*)d_in[3];
    const float* Wl    = (const float*)d_in[4];
    const float* bl    = (const float*)d_in[5];
    const float* gamma = (const float*)d_in[6];
    const float* beta  = (const float*)d_in[7];
    const float* Wfc   = (const float*)d_in[8];
    const float* bfc   = (const float*)d_in[9];
    float* out = (float*)d_out;

    const int N     = in_sizes[0] / 3;
    const int E     = in_sizes[1] / 2;
    const int STEPS = in_sizes[4] / 36;
    const int* src = edges;
    const int* dst = edges + E;
    const int B = (N + NPB - 1) / NPB;   // 391 for N=200000

    char* ws = (char*)d_ws;
    size_t off = 0;
    auto alloc = [&](size_t bytes) -> void* {
        void* p = ws + off;
        off += (bytes + 255) & ~(size_t)255;
        return p;
    };
    int*      bcount = (int*)alloc((size_t)B * sizeof(int));
    int*      boff   = (int*)alloc((size_t)(B + 1) * sizeof(int));
    int*      bcur   = (int*)alloc((size_t)B * sizeof(int));
    int*      ptr    = (int*)alloc((size_t)(N + 1) * sizeof(int));
    float*    dinv   = (float*)alloc((size_t)N * sizeof(float));
    float*    sqd    = (float*)alloc((size_t)N * sizeof(float));
    unsigned* packed = (unsigned*)alloc((size_t)E * sizeof(unsigned));
    int*      csr    = (int*)alloc((size_t)E * sizeof(int));
    float*    xs3    = (float*)alloc((size_t)N * 4 * sizeof(float));
    float*    xsa    = (float*)alloc((size_t)N * 8 * sizeof(float));
    float*    xsb    = (float*)alloc((size_t)N * 8 * sizeof(float));
    __half*   xha    = (__half*)alloc((size_t)N * 8 * sizeof(__half));
    __half*   xhb    = (__half*)alloc((size_t)N * 8 * sizeof(__half));
    (void)ws_size;

    const int gS = (E + TILE - 1) / TILE;   // 782
    const int gC = (N + 3) / 4;

    hipMemsetAsync(bcount, 0, (size_t)B * sizeof(int), stream);
    k_hist<<<gS, 512, 0, stream>>>(dst, bcount, E, B);
    k_bscan<<<1, 512, 0, stream>>>(bcount, boff, bcur, ptr, B, N, E);
    k_scatter<<<gS, 512, 0, stream>>>(src, dst, bcur, packed, E, B);
    k_fine<<<B, 512, 0, stream>>>(boff, packed, csr, ptr, dinv, sqd, node, xs3, N);

    // Conv 1 (F=3): xsa/xha = dinv * ((A_hat @ node) @ W1 + b1)
    k_conv<0><<<gC, 256, 0, stream>>>(ptr, csr, dinv, sqd, xs3, nullptr, W1, b1,
                                      nullptr, nullptr, nullptr, nullptr,
                                      xsa, xha, nullptr, N);

    float* xscur = xsa;   __half* xhcur = xha;
    float* xsnxt = xsb;   __half* xhnxt = xhb;
    for (int i = 0; i < STEPS; ++i) {
        const float* W  = Wl + (size_t)i * 36;
        const float* bb = bl + (size_t)i * 6;
        const float* g  = gamma + (size_t)i * 6;
        const float* be = beta + (size_t)i * 6;
        if (i == STEPS - 1) {
            k_conv<2><<<gC, 256, 0, stream>>>(ptr, csr, dinv, sqd, xscur, xhcur, W, bb,
                                              g, be, Wfc, bfc, nullptr, nullptr, out, N);
        } else {
            k_conv<1><<<gC, 256, 0, stream>>>(ptr, csr, dinv, sqd, xscur, xhcur, W, bb,
                                              g, be, nullptr, nullptr, xsnxt, xhnxt, nullptr, N);
        }
        float* t1 = xscur; xscur = xsnxt; xsnxt = t1;
        __half* t2 = xhcur; xhcur = xhnxt; xhnxt = t2;
    }
}

// Round 8
// 768.616 us; speedup vs baseline: 3.5215x; 1.2381x over previous
//
#include <hip/hip_runtime.h>
#include <hip/hip_fp16.h>
#include <cstdint>

#define EPSLN 1e-5f
#define NPB 512          // nodes per bucket (power of 2)
#define NPB_SHIFT 9
#define MAXB 512         // max buckets (N <= 262144)
#define TILE 16384       // edges per sort tile (LDS staging = 64KB)
#define SRC_BITS 18      // src id fits 18 bits (N <= 262144)
#define SRC_MASK 0x3FFFF

// ---------------------------------------------------------------------------
// Pass 1: per-bucket histogram of dst (int4-vectorized stream)
// ---------------------------------------------------------------------------
__global__ __launch_bounds__(512) void k_hist(const int* __restrict__ dst,
                                              int* __restrict__ bcount, int E, int B) {
    __shared__ int hist[MAXB];
    if (threadIdx.x < B) hist[threadIdx.x] = 0;
    __syncthreads();
    int beg = blockIdx.x * TILE;
    int end = min(beg + TILE, E);
    if (end - beg == TILE) {
        const int4* d4 = (const int4*)(dst + beg);
#pragma unroll
        for (int k = 0; k < TILE / 512 / 4; ++k) {
            int4 q = d4[threadIdx.x + k * 512];
            atomicAdd(&hist[q.x >> NPB_SHIFT], 1);
            atomicAdd(&hist[q.y >> NPB_SHIFT], 1);
            atomicAdd(&hist[q.z >> NPB_SHIFT], 1);
            atomicAdd(&hist[q.w >> NPB_SHIFT], 1);
        }
    } else {
        for (int i = beg + threadIdx.x; i < end; i += 512)
            atomicAdd(&hist[dst[i] >> NPB_SHIFT], 1);
    }
    __syncthreads();
    if (threadIdx.x < B && hist[threadIdx.x])
        atomicAdd(&bcount[threadIdx.x], hist[threadIdx.x]);
}

// ---------------------------------------------------------------------------
// Pass 2: scan bucket counts -> boff / bcur; seed ptr[N]=E
// ---------------------------------------------------------------------------
__global__ __launch_bounds__(512) void k_bscan(const int* __restrict__ bcount,
                                               int* __restrict__ boff,
                                               int* __restrict__ bcur,
                                               int* __restrict__ ptr,
                                               int B, int N, int E) {
    __shared__ int sm[512];
    int v = (threadIdx.x < B) ? bcount[threadIdx.x] : 0;
    sm[threadIdx.x] = v;
    __syncthreads();
    for (int off = 1; off < 512; off <<= 1) {
        int t = (threadIdx.x >= off) ? sm[threadIdx.x - off] : 0;
        __syncthreads();
        sm[threadIdx.x] += t;
        __syncthreads();
    }
    if (threadIdx.x < B) {
        int e = sm[threadIdx.x] - v;
        boff[threadIdx.x] = e;
        bcur[threadIdx.x] = e;
    }
    if (threadIdx.x == 0) { boff[B] = E; ptr[N] = E; }
}

// ---------------------------------------------------------------------------
// Pass 3: LDS-staged bucket scatter -> coalesced per-bucket bursts.
// ---------------------------------------------------------------------------
__global__ __launch_bounds__(512) void k_scatter(const int* __restrict__ src,
                                                 const int* __restrict__ dst,
                                                 int* __restrict__ bcur,
                                                 unsigned* __restrict__ packed,
                                                 int E, int B) {
    __shared__ unsigned stg[TILE];     // 64 KB staging
    __shared__ int hist[MAXB];         // per-bucket count, then placement cursor
    __shared__ int lbase[MAXB + 1];    // exclusive scan (local segment bases)
    __shared__ int gbase[MAXB];        // reserved global chunk base
    __shared__ int sm[512];
    int tid = threadIdx.x;
    if (tid < B) hist[tid] = 0;
    __syncthreads();

    int beg = blockIdx.x * TILE;
    int end = min(beg + TILE, E);
    int cnt = end - beg;

    // Phase A: histogram
    for (int i = beg + tid; i < end; i += 512)
        atomicAdd(&hist[dst[i] >> NPB_SHIFT], 1);
    __syncthreads();

    // Phase B: local scan + global reservation
    int v = (tid < B) ? hist[tid] : 0;
    sm[tid] = v;
    __syncthreads();
    for (int off = 1; off < 512; off <<= 1) {
        int t = (tid >= off) ? sm[tid - off] : 0;
        __syncthreads();
        sm[tid] += t;
        __syncthreads();
    }
    if (tid < B) {
        lbase[tid] = sm[tid] - v;
        gbase[tid] = v ? atomicAdd(&bcur[tid], v) : 0;
        hist[tid] = 0;  // becomes placement cursor
    }
    if (tid == 0) lbase[B] = cnt;
    __syncthreads();

    // Phase C: place packed words into staging, sorted by bucket
    for (int i = beg + tid; i < end; i += 512) {
        int d = dst[i];
        int s = src[i];
        int bkt = d >> NPB_SHIFT;
        int pos = lbase[bkt] + atomicAdd(&hist[bkt], 1);
        stg[pos] = ((unsigned)(d & (NPB - 1)) << SRC_BITS) | (unsigned)s;
    }
    __syncthreads();

    // Phase D: linear drain; coalesced full-line bursts per bucket chunk
    for (int j = tid; j < cnt; j += 512) {
        int lo = 0, hi = B;
        while (hi - lo > 1) {
            int mid = (lo + hi) >> 1;
            if (lbase[mid] <= j) lo = mid; else hi = mid;
        }
        packed[gbase[lo] + (j - lbase[lo])] = stg[j];
    }
}

// ---------------------------------------------------------------------------
// Pass 4: per-bucket fine sort + fused degree/dinv/ptr/xs3 production.
// ---------------------------------------------------------------------------
__global__ __launch_bounds__(512) void k_fine(const int* __restrict__ boff,
                                              const unsigned* __restrict__ packed,
                                              int* __restrict__ csr,
                                              int* __restrict__ ptr,
                                              float* __restrict__ dinv,
                                              float* __restrict__ sqd,
                                              const float* __restrict__ node,
                                              float* __restrict__ xs3,   // [N,4]
                                              int N) {
    __shared__ int hist[NPB];
    __shared__ int cur[NPB];
    int b = blockIdx.x;
    int beg = boff[b], end = boff[b + 1];
    int tid = threadIdx.x;
    hist[tid] = 0;
    __syncthreads();
    for (int i = beg + tid; i < end; i += 512)
        atomicAdd(&hist[packed[i] >> SRC_BITS], 1);
    __syncthreads();
    int hv = hist[tid];
    cur[tid] = hv;
    __syncthreads();
    for (int off = 1; off < NPB; off <<= 1) {
        int t = (tid >= off) ? cur[tid - off] : 0;
        __syncthreads();
        cur[tid] += t;
        __syncthreads();
    }
    int ex = cur[tid] - hv;  // exclusive
    int v = b * NPB + tid;
    if (v < N) {
        ptr[v] = beg + ex;
        float c = (float)(hv + 1);      // +1: self-loop
        float di = rsqrtf(c);
        dinv[v] = di;
        sqd[v] = sqrtf(c);              // = 1/di, residual reconstruction
        xs3[(size_t)v * 4 + 0] = di * node[(size_t)v * 3 + 0];
        xs3[(size_t)v * 4 + 1] = di * node[(size_t)v * 3 + 1];
        xs3[(size_t)v * 4 + 2] = di * node[(size_t)v * 3 + 2];
        xs3[(size_t)v * 4 + 3] = 0.f;
    }
    cur[tid] = ex;  // placement cursor
    __syncthreads();
    for (int i = beg + tid; i < end; i += 512) {
        unsigned w = packed[i];
        int dl = (int)(w >> SRC_BITS);
        int pos = atomicAdd(&cur[dl], 1);
        csr[beg + pos] = (int)(w & SRC_MASK);
    }
}

// ---------------------------------------------------------------------------
// Fused conv: 4 nodes per wave (16-lane segments) -> 4 independent gather
// chains per wave, 4-step shuffle tree, epilogue on lanes {0,16,32,48}.
// MODE 0: first conv (F=3, fp32 gathers). MODE 1: mid. MODE 2: final -> out.
// ---------------------------------------------------------------------------
template <int MODE>
__global__ __launch_bounds__(512) void k_conv(const int* __restrict__ ptr,
                                              const int* __restrict__ csr,
                                              const float* __restrict__ dinv,
                                              const float* __restrict__ sqd,
                                              const float* __restrict__ xs,   // fp32: MODE0 [N,4], else [N,8]
                                              const __half* __restrict__ xsh, // fp16 [N,8] (MODE1/2)
                                              const float* __restrict__ W,
                                              const float* __restrict__ b,
                                              const float* __restrict__ gamma,
                                              const float* __restrict__ beta,
                                              const float* __restrict__ Wfc,
                                              const float* __restrict__ bfc,
                                              float* __restrict__ xsout,      // fp32 [N,8]
                                              __half* __restrict__ xhout,     // fp16 [N,8]
                                              float* __restrict__ outfc,      // [N,3]
                                              int N) {
    constexpr int F = (MODE == 0) ? 3 : 6;
    int wave = threadIdx.x >> 6;
    int lane = threadIdx.x & 63;
    int sub  = lane >> 4;        // 0..3: which node in this wave
    int li   = lane & 15;        // lane within 16-lane segment
    int v = (blockIdx.x * 8 + wave) * 4 + sub;
    bool valid = v < N;
    int beg = 0, end = 0;
    if (valid) { beg = ptr[v]; end = ptr[v + 1]; }

    float a0 = 0.f, a1 = 0.f, a2 = 0.f, a3 = 0.f, a4 = 0.f, a5 = 0.f;
    if constexpr (F == 3) {
        const float4* x4 = (const float4*)xs;
        for (int i = beg + li; i < end; i += 16) {
            float4 p = x4[csr[i]];
            a0 += p.x; a1 += p.y; a2 += p.z;
        }
        if (valid && li == 0) { float4 p = x4[v]; a0 += p.x; a1 += p.y; a2 += p.z; }
    } else {
        const float4* xh4 = (const float4*)xsh;  // 8 halves = 16B
        for (int i = beg + li; i < end; i += 16) {
            float4 raw = xh4[csr[i]];
            const __half2* h2 = (const __half2*)&raw;
            float2 p0 = __half22float2(h2[0]);
            float2 p1 = __half22float2(h2[1]);
            float2 p2 = __half22float2(h2[2]);
            a0 += p0.x; a1 += p0.y; a2 += p1.x; a3 += p1.y; a4 += p2.x; a5 += p2.y;
        }
        if (valid && li == 0) {  // self-loop, fp32
            const float* r = xs + (size_t)v * 8;
            float4 p = *(const float4*)r;
            float2 q = *(const float2*)(r + 4);
            a0 += p.x; a1 += p.y; a2 += p.z; a3 += p.w; a4 += q.x; a5 += q.y;
        }
    }
    // 16-lane tree reduce (offsets stay within each segment for lanes that matter)
#pragma unroll
    for (int off = 8; off >= 1; off >>= 1) {
        a0 += __shfl_down(a0, off);
        a1 += __shfl_down(a1, off);
        a2 += __shfl_down(a2, off);
        if constexpr (F == 6) {
            a3 += __shfl_down(a3, off);
            a4 += __shfl_down(a4, off);
            a5 += __shfl_down(a5, off);
        }
    }
    if (li != 0 || !valid) return;

    float di = dinv[v];
    float t[F];
    t[0] = di * a0; t[1] = di * a1; t[2] = di * a2;
    if constexpr (F == 6) { t[3] = di * a3; t[4] = di * a4; t[5] = di * a5; }

    float y[6];
#pragma unroll
    for (int j = 0; j < 6; ++j) {
        float acc = b[j];
#pragma unroll
        for (int k = 0; k < F; ++k) acc += t[k] * W[k * 6 + j];
        y[j] = acc;
    }

    if constexpr (MODE == 0) {
        float* o = xsout + (size_t)v * 8;
        *(float4*)o = make_float4(di * y[0], di * y[1], di * y[2], di * y[3]);
        *(float2*)(o + 4) = make_float2(di * y[4], di * y[5]);
        __half2* oh = (__half2*)(xhout + (size_t)v * 8);
        oh[0] = __floats2half2_rn(di * y[0], di * y[1]);
        oh[1] = __floats2half2_rn(di * y[2], di * y[3]);
        oh[2] = __floats2half2_rn(di * y[4], di * y[5]);
        oh[3] = __floats2half2_rn(0.f, 0.f);
    } else {
        float mu = 0.f;
#pragma unroll
        for (int j = 0; j < 6; ++j) mu += y[j];
        mu *= (1.f / 6.f);
        float var = 0.f;
#pragma unroll
        for (int j = 0; j < 6; ++j) { float dl = y[j] - mu; var += dl * dl; }
        var *= (1.f / 6.f);
        float rs = rsqrtf(var + EPSLN);
        float sq = sqd[v];
        const float* xr = xs + (size_t)v * 8;   // residual = xs * sqrt(deg+1)
        float r[6];
#pragma unroll
        for (int j = 0; j < 6; ++j) {
            float z = (y[j] - mu) * rs * gamma[j] + beta[j] + xr[j] * sq;
            r[j] = z > 0.f ? z : 0.f;
        }
        if constexpr (MODE == 1) {
            float* o = xsout + (size_t)v * 8;
            *(float4*)o = make_float4(di * r[0], di * r[1], di * r[2], di * r[3]);
            *(float2*)(o + 4) = make_float2(di * r[4], di * r[5]);
            __half2* oh = (__half2*)(xhout + (size_t)v * 8);
            oh[0] = __floats2half2_rn(di * r[0], di * r[1]);
            oh[1] = __floats2half2_rn(di * r[2], di * r[3]);
            oh[2] = __floats2half2_rn(di * r[4], di * r[5]);
            oh[3] = __floats2half2_rn(0.f, 0.f);
        } else {
#pragma unroll
            for (int j = 0; j < 3; ++j) {
                float acc = bfc[j];
#pragma unroll
                for (int k = 0; k < 6; ++k) acc += r[k] * Wfc[k * 3 + j];
                outfc[(size_t)v * 3 + j] = acc;
            }
        }
    }
}

// ---------------------------------------------------------------------------
extern "C" void kernel_launch(void* const* d_in, const int* in_sizes, int n_in,
                              void* d_out, int out_size, void* d_ws, size_t ws_size,
                              hipStream_t stream) {
    const float* node  = (const float*)d_in[0];
    const int*   edges = (const int*)d_in[1];
    const float* W1    = (const float*)d_in[2];
    const float* b1    = (const float*)d_in[3];
    const float* Wl    = (const float*)d_in[4];
    const float* bl    = (const float*)d_in[5];
    const float* gamma = (const float*)d_in[6];
    const float* beta  = (const float*)d_in[7];
    const float* Wfc   = (const float*)d_in[8];
    const float* bfc   = (const float*)d_in[9];
    float* out = (float*)d_out;

    const int N     = in_sizes[0] / 3;
    const int E     = in_sizes[1] / 2;
    const int STEPS = in_sizes[4] / 36;
    const int* src = edges;
    const int* dst = edges + E;
    const int B = (N + NPB - 1) / NPB;   // 391 for N=200000

    char* ws = (char*)d_ws;
    size_t off = 0;
    auto alloc = [&](size_t bytes) -> void* {
        void* p = ws + off;
        off += (bytes + 255) & ~(size_t)255;
        return p;
    };
    int*      bcount = (int*)alloc((size_t)B * sizeof(int));
    int*      boff   = (int*)alloc((size_t)(B + 1) * sizeof(int));
    int*      bcur   = (int*)alloc((size_t)B * sizeof(int));
    int*      ptr    = (int*)alloc((size_t)(N + 1) * sizeof(int));
    float*    dinv   = (float*)alloc((size_t)N * sizeof(float));
    float*    sqd    = (float*)alloc((size_t)N * sizeof(float));
    unsigned* packed = (unsigned*)alloc((size_t)E * sizeof(unsigned));
    int*      csr    = (int*)alloc((size_t)E * sizeof(int));
    float*    xs3    = (float*)alloc((size_t)N * 4 * sizeof(float));
    float*    xsa    = (float*)alloc((size_t)N * 8 * sizeof(float));
    float*    xsb    = (float*)alloc((size_t)N * 8 * sizeof(float));
    __half*   xha    = (__half*)alloc((size_t)N * 8 * sizeof(__half));
    __half*   xhb    = (__half*)alloc((size_t)N * 8 * sizeof(__half));
    (void)ws_size;

    const int gS = (E + TILE - 1) / TILE;   // 782
    const int gC = (N + 31) / 32;           // 4 nodes/wave, 8 waves/block

    hipMemsetAsync(bcount, 0, (size_t)B * sizeof(int), stream);
    k_hist<<<gS, 512, 0, stream>>>(dst, bcount, E, B);
    k_bscan<<<1, 512, 0, stream>>>(bcount, boff, bcur, ptr, B, N, E);
    k_scatter<<<gS, 512, 0, stream>>>(src, dst, bcur, packed, E, B);
    k_fine<<<B, 512, 0, stream>>>(boff, packed, csr, ptr, dinv, sqd, node, xs3, N);

    // Conv 1 (F=3): xsa/xha = dinv * ((A_hat @ node) @ W1 + b1)
    k_conv<0><<<gC, 512, 0, stream>>>(ptr, csr, dinv, sqd, xs3, nullptr, W1, b1,
                                      nullptr, nullptr, nullptr, nullptr,
                                      xsa, xha, nullptr, N);

    float* xscur = xsa;   __half* xhcur = xha;
    float* xsnxt = xsb;   __half* xhnxt = xhb;
    for (int i = 0; i < STEPS; ++i) {
        const float* W  = Wl + (size_t)i * 36;
        const float* bb = bl + (size_t)i * 6;
        const float* g  = gamma + (size_t)i * 6;
        const float* be = beta + (size_t)i * 6;
        if (i == STEPS - 1) {
            k_conv<2><<<gC, 512, 0, stream>>>(ptr, csr, dinv, sqd, xscur, xhcur, W, bb,
                                              g, be, Wfc, bfc, nullptr, nullptr, out, N);
        } else {
            k_conv<1><<<gC, 512, 0, stream>>>(ptr, csr, dinv, sqd, xscur, xhcur, W, bb,
                                              g, be, nullptr, nullptr, xsnxt, xhnxt, nullptr, N);
        }
        float* t1 = xscur; xscur = xsnxt; xsnxt = t1;
        __half* t2 = xhcur; xhcur = xhnxt; xhnxt = t2;
    }
}

// Round 9
// 725.512 us; speedup vs baseline: 3.7308x; 1.0594x over previous
//
#include <hip/hip_runtime.h>
#include <hip/hip_fp16.h>
#include <cstdint>

#define EPSLN 1e-5f
#define NPB 256          // nodes per bucket (power of 2)
#define NPB_SHIFT 8
#define MAXB 1024        // max buckets (N <= 262144)
#define TILE 16384       // edges per sort tile (LDS staging = 64KB)
#define SRC_BITS 18      // src id fits 18 bits (N <= 262144)
#define SRC_MASK 0x3FFFF

// ---------------------------------------------------------------------------
// Init per-bucket global cursors to fixed-capacity bases: bcur[b] = b*CAP
// ---------------------------------------------------------------------------
__global__ __launch_bounds__(512) void k_init(int* __restrict__ bcur, int B, int cap) {
    int b = blockIdx.x * 512 + threadIdx.x;
    if (b < B) bcur[b] = b * cap;
}

// ---------------------------------------------------------------------------
// Single-pass rank-based scatter. Per tile: one LDS atomic per edge yields
// (bucket, within-bucket rank); words cached in VGPRs; placement into LDS
// staging is atomic-free; linear drain emits coalesced per-bucket bursts.
// ---------------------------------------------------------------------------
__global__ __launch_bounds__(512) void k_scatter(const int* __restrict__ src,
                                                 const int* __restrict__ dst,
                                                 int* __restrict__ bcur,
                                                 unsigned* __restrict__ packed,
                                                 int E, int B) {
    __shared__ unsigned stg[TILE];     // 64 KB staging
    __shared__ int hist[MAXB];         // counts, then reused as gbase
    __shared__ int lbase[MAXB + 1];    // exclusive scan (local segment bases)
    __shared__ int sm[MAXB];           // scan workspace
    int tid = threadIdx.x;
    int i0 = tid, i1 = tid + 512;
    hist[i0] = 0; hist[i1] = 0;
    __syncthreads();

    int beg = blockIdx.x * TILE;
    int end = min(beg + TILE, E);
    int cnt = end - beg;

    unsigned w[32];   // packed payload words
    unsigned m[32];   // meta: (bkt<<14)|rank, 0xFFFFFFFF = invalid

    // Phase A: load + histogram + rank (single pass over src/dst)
    if (cnt == TILE && ((E & 3) == 0)) {
        const int4* d4 = (const int4*)(dst + beg);
        const int4* s4 = (const int4*)(src + beg);
#pragma unroll
        for (int k = 0; k < 8; ++k) {
            int4 d = d4[tid + k * 512];
            int4 s = s4[tid + k * 512];
            int b0 = d.x >> NPB_SHIFT, b1 = d.y >> NPB_SHIFT;
            int b2 = d.z >> NPB_SHIFT, b3 = d.w >> NPB_SHIFT;
            int r0 = atomicAdd(&hist[b0], 1);
            int r1 = atomicAdd(&hist[b1], 1);
            int r2 = atomicAdd(&hist[b2], 1);
            int r3 = atomicAdd(&hist[b3], 1);
            w[4 * k + 0] = ((unsigned)(d.x & (NPB - 1)) << SRC_BITS) | (unsigned)s.x;
            w[4 * k + 1] = ((unsigned)(d.y & (NPB - 1)) << SRC_BITS) | (unsigned)s.y;
            w[4 * k + 2] = ((unsigned)(d.z & (NPB - 1)) << SRC_BITS) | (unsigned)s.z;
            w[4 * k + 3] = ((unsigned)(d.w & (NPB - 1)) << SRC_BITS) | (unsigned)s.w;
            m[4 * k + 0] = ((unsigned)b0 << 14) | (unsigned)r0;
            m[4 * k + 1] = ((unsigned)b1 << 14) | (unsigned)r1;
            m[4 * k + 2] = ((unsigned)b2 << 14) | (unsigned)r2;
            m[4 * k + 3] = ((unsigned)b3 << 14) | (unsigned)r3;
        }
    } else {
#pragma unroll
        for (int k = 0; k < 32; ++k) {
            int i = beg + tid + k * 512;
            if (i < end) {
                int d = dst[i];
                int s = src[i];
                int bkt = d >> NPB_SHIFT;
                int r = atomicAdd(&hist[bkt], 1);
                w[k] = ((unsigned)(d & (NPB - 1)) << SRC_BITS) | (unsigned)s;
                m[k] = ((unsigned)bkt << 14) | (unsigned)r;
            } else {
                m[k] = 0xFFFFFFFFu;
            }
        }
    }
    __syncthreads();

    // Phase B: scan counts -> lbase; reserve global chunks (gbase into hist)
    int v0 = hist[i0], v1 = hist[i1];
    sm[i0] = v0; sm[i1] = v1;
    __syncthreads();
    for (int off = 1; off < MAXB; off <<= 1) {
        int t0 = (i0 >= off) ? sm[i0 - off] : 0;
        int t1 = (i1 >= off) ? sm[i1 - off] : 0;
        __syncthreads();
        sm[i0] += t0; sm[i1] += t1;
        __syncthreads();
    }
    lbase[i0] = sm[i0] - v0;
    lbase[i1] = sm[i1] - v1;
    if (i0 < B) hist[i0] = v0 ? atomicAdd(&bcur[i0], v0) : 0;
    if (i1 < B) hist[i1] = v1 ? atomicAdd(&bcur[i1], v1) : 0;
    if (tid == 0) lbase[B] = cnt;
    __syncthreads();

    // Phase C: place into staging (no atomics; rank precomputed)
#pragma unroll
    for (int k = 0; k < 32; ++k) {
        if (m[k] != 0xFFFFFFFFu) {
            int bkt = (int)(m[k] >> 14);
            int r   = (int)(m[k] & 16383u);
            stg[lbase[bkt] + r] = w[k];
        }
    }
    __syncthreads();

    // Phase D: linear drain; coalesced full-line bursts per bucket chunk
    for (int j = tid; j < cnt; j += 512) {
        int lo = 0, hi = B;
        while (hi - lo > 1) {
            int mid = (lo + hi) >> 1;
            if (lbase[mid] <= j) lo = mid; else hi = mid;
        }
        packed[hist[lo] + (j - lbase[lo])] = stg[j];
    }
}

// ---------------------------------------------------------------------------
// Per-bucket fine sort + fused degree/dinv/ptr2/xs3 production.
// ---------------------------------------------------------------------------
__global__ __launch_bounds__(256) void k_fine(const int* __restrict__ bcur,
                                              const unsigned* __restrict__ packed,
                                              int* __restrict__ csr,
                                              int2* __restrict__ ptr2,
                                              float* __restrict__ dinv,
                                              float* __restrict__ sqd,
                                              const float* __restrict__ node,
                                              float* __restrict__ xs3,   // [N,4]
                                              int N, int cap) {
    __shared__ int hist[NPB];
    __shared__ int cur[NPB];
    int b = blockIdx.x;
    int beg = b * cap;
    int end = bcur[b];           // final cursor = beg + count
    int tid = threadIdx.x;
    hist[tid] = 0;
    __syncthreads();
    for (int i = beg + tid; i < end; i += 256)
        atomicAdd(&hist[packed[i] >> SRC_BITS], 1);
    __syncthreads();
    int hv = hist[tid];
    cur[tid] = hv;
    __syncthreads();
    for (int off = 1; off < NPB; off <<= 1) {
        int t = (tid >= off) ? cur[tid - off] : 0;
        __syncthreads();
        cur[tid] += t;
        __syncthreads();
    }
    int ex = cur[tid] - hv;  // exclusive
    int v = b * NPB + tid;
    if (v < N) {
        ptr2[v] = make_int2(beg + ex, beg + ex + hv);
        float c = (float)(hv + 1);      // +1: self-loop
        float di = rsqrtf(c);
        dinv[v] = di;
        sqd[v] = sqrtf(c);              // = 1/di, residual reconstruction
        xs3[(size_t)v * 4 + 0] = di * node[(size_t)v * 3 + 0];
        xs3[(size_t)v * 4 + 1] = di * node[(size_t)v * 3 + 1];
        xs3[(size_t)v * 4 + 2] = di * node[(size_t)v * 3 + 2];
        xs3[(size_t)v * 4 + 3] = 0.f;
    }
    cur[tid] = ex;  // placement cursor
    __syncthreads();
    for (int i = beg + tid; i < end; i += 256) {
        unsigned w = packed[i];
        int dl = (int)(w >> SRC_BITS);
        int pos = atomicAdd(&cur[dl], 1);
        csr[beg + pos] = (int)(w & SRC_MASK);
    }
}

// ---------------------------------------------------------------------------
// Fused conv: 4 nodes per wave (16-lane segments), int2 segment bounds.
// MODE 0: first conv (F=3, fp32 gathers). MODE 1: mid. MODE 2: final -> out.
// ---------------------------------------------------------------------------
template <int MODE>
__global__ __launch_bounds__(512) void k_conv(const int2* __restrict__ ptr2,
                                              const int* __restrict__ csr,
                                              const float* __restrict__ dinv,
                                              const float* __restrict__ sqd,
                                              const float* __restrict__ xs,   // fp32: MODE0 [N,4], else [N,8]
                                              const __half* __restrict__ xsh, // fp16 [N,8] (MODE1/2)
                                              const float* __restrict__ W,
                                              const float* __restrict__ b,
                                              const float* __restrict__ gamma,
                                              const float* __restrict__ beta,
                                              const float* __restrict__ Wfc,
                                              const float* __restrict__ bfc,
                                              float* __restrict__ xsout,      // fp32 [N,8]
                                              __half* __restrict__ xhout,     // fp16 [N,8]
                                              float* __restrict__ outfc,      // [N,3]
                                              int N) {
    constexpr int F = (MODE == 0) ? 3 : 6;
    int wave = threadIdx.x >> 6;
    int lane = threadIdx.x & 63;
    int sub  = lane >> 4;        // 0..3: which node in this wave
    int li   = lane & 15;        // lane within 16-lane segment
    int v = (blockIdx.x * 8 + wave) * 4 + sub;
    bool valid = v < N;
    int beg = 0, end = 0;
    if (valid) { int2 p = ptr2[v]; beg = p.x; end = p.y; }

    float a0 = 0.f, a1 = 0.f, a2 = 0.f, a3 = 0.f, a4 = 0.f, a5 = 0.f;
    if constexpr (F == 3) {
        const float4* x4 = (const float4*)xs;
        for (int i = beg + li; i < end; i += 16) {
            float4 p = x4[csr[i]];
            a0 += p.x; a1 += p.y; a2 += p.z;
        }
        if (valid && li == 0) { float4 p = x4[v]; a0 += p.x; a1 += p.y; a2 += p.z; }
    } else {
        const float4* xh4 = (const float4*)xsh;  // 8 halves = 16B
        for (int i = beg + li; i < end; i += 16) {
            float4 raw = xh4[csr[i]];
            const __half2* h2 = (const __half2*)&raw;
            float2 p0 = __half22float2(h2[0]);
            float2 p1 = __half22float2(h2[1]);
            float2 p2 = __half22float2(h2[2]);
            a0 += p0.x; a1 += p0.y; a2 += p1.x; a3 += p1.y; a4 += p2.x; a5 += p2.y;
        }
        if (valid && li == 0) {  // self-loop, fp32
            const float* r = xs + (size_t)v * 8;
            float4 p = *(const float4*)r;
            float2 q = *(const float2*)(r + 4);
            a0 += p.x; a1 += p.y; a2 += p.z; a3 += p.w; a4 += q.x; a5 += q.y;
        }
    }
#pragma unroll
    for (int off = 8; off >= 1; off >>= 1) {
        a0 += __shfl_down(a0, off);
        a1 += __shfl_down(a1, off);
        a2 += __shfl_down(a2, off);
        if constexpr (F == 6) {
            a3 += __shfl_down(a3, off);
            a4 += __shfl_down(a4, off);
            a5 += __shfl_down(a5, off);
        }
    }
    if (li != 0 || !valid) return;

    float di = dinv[v];
    float t[F];
    t[0] = di * a0; t[1] = di * a1; t[2] = di * a2;
    if constexpr (F == 6) { t[3] = di * a3; t[4] = di * a4; t[5] = di * a5; }

    float y[6];
#pragma unroll
    for (int j = 0; j < 6; ++j) {
        float acc = b[j];
#pragma unroll
        for (int k = 0; k < F; ++k) acc += t[k] * W[k * 6 + j];
        y[j] = acc;
    }

    if constexpr (MODE == 0) {
        float* o = xsout + (size_t)v * 8;
        *(float4*)o = make_float4(di * y[0], di * y[1], di * y[2], di * y[3]);
        *(float2*)(o + 4) = make_float2(di * y[4], di * y[5]);
        __half2* oh = (__half2*)(xhout + (size_t)v * 8);
        oh[0] = __floats2half2_rn(di * y[0], di * y[1]);
        oh[1] = __floats2half2_rn(di * y[2], di * y[3]);
        oh[2] = __floats2half2_rn(di * y[4], di * y[5]);
        oh[3] = __floats2half2_rn(0.f, 0.f);
    } else {
        float mu = 0.f;
#pragma unroll
        for (int j = 0; j < 6; ++j) mu += y[j];
        mu *= (1.f / 6.f);
        float var = 0.f;
#pragma unroll
        for (int j = 0; j < 6; ++j) { float dl = y[j] - mu; var += dl * dl; }
        var *= (1.f / 6.f);
        float rs = rsqrtf(var + EPSLN);
        float sq = sqd[v];
        const float* xr = xs + (size_t)v * 8;   // residual = xs * sqrt(deg+1)
        float r[6];
#pragma unroll
        for (int j = 0; j < 6; ++j) {
            float z = (y[j] - mu) * rs * gamma[j] + beta[j] + xr[j] * sq;
            r[j] = z > 0.f ? z : 0.f;
        }
        if constexpr (MODE == 1) {
            float* o = xsout + (size_t)v * 8;
            *(float4*)o = make_float4(di * r[0], di * r[1], di * r[2], di * r[3]);
            *(float2*)(o + 4) = make_float2(di * r[4], di * r[5]);
            __half2* oh = (__half2*)(xhout + (size_t)v * 8);
            oh[0] = __floats2half2_rn(di * r[0], di * r[1]);
            oh[1] = __floats2half2_rn(di * r[2], di * r[3]);
            oh[2] = __floats2half2_rn(di * r[4], di * r[5]);
            oh[3] = __floats2half2_rn(0.f, 0.f);
        } else {
#pragma unroll
            for (int j = 0; j < 3; ++j) {
                float acc = bfc[j];
#pragma unroll
                for (int k = 0; k < 6; ++k) acc += r[k] * Wfc[k * 3 + j];
                outfc[(size_t)v * 3 + j] = acc;
            }
        }
    }
}

// ---------------------------------------------------------------------------
extern "C" void kernel_launch(void* const* d_in, const int* in_sizes, int n_in,
                              void* d_out, int out_size, void* d_ws, size_t ws_size,
                              hipStream_t stream) {
    const float* node  = (const float*)d_in[0];
    const int*   edges = (const int*)d_in[1];
    const float* W1    = (const float*)d_in[2];
    const float* b1    = (const float*)d_in[3];
    const float* Wl    = (const float*)d_in[4];
    const float* bl    = (const float*)d_in[5];
    const float* gamma = (const float*)d_in[6];
    const float* beta  = (const float*)d_in[7];
    const float* Wfc   = (const float*)d_in[8];
    const float* bfc   = (const float*)d_in[9];
    float* out = (float*)d_out;

    const int N     = in_sizes[0] / 3;
    const int E     = in_sizes[1] / 2;
    const int STEPS = in_sizes[4] / 36;
    const int* src = edges;
    const int* dst = edges + E;
    const int B = (N + NPB - 1) / NPB;   // 782 for N=200000

    // Fixed bucket capacity: mean + ~8 sigma, 256-aligned
    const int mean = E / B;
    const int CAP = (mean + 8 * (int)(sqrt((double)mean) + 1) + 255) & ~255;

    char* ws = (char*)d_ws;
    size_t off = 0;
    auto alloc = [&](size_t bytes) -> void* {
        void* p = ws + off;
        off += (bytes + 255) & ~(size_t)255;
        return p;
    };
    int*      bcur   = (int*)alloc((size_t)B * sizeof(int));
    int2*     ptr2   = (int2*)alloc((size_t)N * sizeof(int2));
    float*    dinv   = (float*)alloc((size_t)N * sizeof(float));
    float*    sqd    = (float*)alloc((size_t)N * sizeof(float));
    unsigned* packed = (unsigned*)alloc((size_t)B * CAP * sizeof(unsigned));
    int*      csr    = (int*)alloc((size_t)B * CAP * sizeof(int));
    float*    xs3    = (float*)alloc((size_t)N * 4 * sizeof(float));
    float*    xsa    = (float*)alloc((size_t)N * 8 * sizeof(float));
    float*    xsb    = (float*)alloc((size_t)N * 8 * sizeof(float));
    __half*   xha    = (__half*)alloc((size_t)N * 8 * sizeof(__half));
    __half*   xhb    = (__half*)alloc((size_t)N * 8 * sizeof(__half));
    (void)ws_size;

    const int gS = (E + TILE - 1) / TILE;   // 782
    const int gC = (N + 31) / 32;           // 4 nodes/wave, 8 waves/block

    k_init<<<(B + 511) / 512, 512, 0, stream>>>(bcur, B, CAP);
    k_scatter<<<gS, 512, 0, stream>>>(src, dst, bcur, packed, E, B);
    k_fine<<<B, NPB, 0, stream>>>(bcur, packed, csr, ptr2, dinv, sqd, node, xs3, N, CAP);

    // Conv 1 (F=3): xsa/xha = dinv * ((A_hat @ node) @ W1 + b1)
    k_conv<0><<<gC, 512, 0, stream>>>(ptr2, csr, dinv, sqd, xs3, nullptr, W1, b1,
                                      nullptr, nullptr, nullptr, nullptr,
                                      xsa, xha, nullptr, N);

    float* xscur = xsa;   __half* xhcur = xha;
    float* xsnxt = xsb;   __half* xhnxt = xhb;
    for (int i = 0; i < STEPS; ++i) {
        const float* W  = Wl + (size_t)i * 36;
        const float* bb = bl + (size_t)i * 6;
        const float* g  = gamma + (size_t)i * 6;
        const float* be = beta + (size_t)i * 6;
        if (i == STEPS - 1) {
            k_conv<2><<<gC, 512, 0, stream>>>(ptr2, csr, dinv, sqd, xscur, xhcur, W, bb,
                                              g, be, Wfc, bfc, nullptr, nullptr, out, N);
        } else {
            k_conv<1><<<gC, 512, 0, stream>>>(ptr2, csr, dinv, sqd, xscur, xhcur, W, bb,
                                              g, be, nullptr, nullptr, xsnxt, xhnxt, nullptr, N);
        }
        float* t1 = xscur; xscur = xsnxt; xsnxt = t1;
        __half* t2 = xhcur; xhcur = xhnxt; xhnxt = t2;
    }
}

// Round 10
// 642.001 us; speedup vs baseline: 4.2160x; 1.1301x over previous
//
#include <hip/hip_runtime.h>
#include <hip/hip_fp16.h>
#include <cstdint>

#define EPSLN 1e-5f
#define NPB 256          // nodes per bucket (power of 2)
#define NPB_SHIFT 8
#define MAXB 1024        // max buckets (N <= 262144)
#define TILE 16384       // edges per sort tile (LDS staging = 64KB)
#define SRC_BITS 18      // src id fits 18 bits (N <= 262144)
#define SRC_MASK 0x3FFFF
#define FCAP 17664       // k_fine LDS staging words; >= CAP (mean+8sigma, 256-aligned)
#define FK 35            // FCAP / 512 rounded up

// ---------------------------------------------------------------------------
// Init per-bucket global cursors to fixed-capacity bases: bcur[b] = b*CAP
// ---------------------------------------------------------------------------
__global__ __launch_bounds__(512) void k_init(int* __restrict__ bcur, int B, int cap) {
    int b = blockIdx.x * 512 + threadIdx.x;
    if (b < B) bcur[b] = b * cap;
}

// ---------------------------------------------------------------------------
// Single-pass rank-based scatter (round-8 proven): one LDS atomic per edge
// yields (bucket, rank); placement atomic-free; linear coalesced drain.
// ---------------------------------------------------------------------------
__global__ __launch_bounds__(512) void k_scatter(const int* __restrict__ src,
                                                 const int* __restrict__ dst,
                                                 int* __restrict__ bcur,
                                                 unsigned* __restrict__ packed,
                                                 int E, int B) {
    __shared__ unsigned stg[TILE];     // 64 KB staging
    __shared__ int hist[MAXB];         // counts, then reused as gbase
    __shared__ int lbase[MAXB + 1];    // exclusive scan (local segment bases)
    __shared__ int sm[MAXB];           // scan workspace
    int tid = threadIdx.x;
    int i0 = tid, i1 = tid + 512;
    hist[i0] = 0; hist[i1] = 0;
    __syncthreads();

    int beg = blockIdx.x * TILE;
    int end = min(beg + TILE, E);
    int cnt = end - beg;

    unsigned w[32];   // packed payload words
    unsigned m[32];   // meta: (bkt<<14)|rank, 0xFFFFFFFF = invalid

    // Phase A: load + histogram + rank (single pass over src/dst)
    if (cnt == TILE && ((E & 3) == 0)) {
        const int4* d4 = (const int4*)(dst + beg);
        const int4* s4 = (const int4*)(src + beg);
#pragma unroll
        for (int k = 0; k < 8; ++k) {
            int4 d = d4[tid + k * 512];
            int4 s = s4[tid + k * 512];
            int b0 = d.x >> NPB_SHIFT, b1 = d.y >> NPB_SHIFT;
            int b2 = d.z >> NPB_SHIFT, b3 = d.w >> NPB_SHIFT;
            int r0 = atomicAdd(&hist[b0], 1);
            int r1 = atomicAdd(&hist[b1], 1);
            int r2 = atomicAdd(&hist[b2], 1);
            int r3 = atomicAdd(&hist[b3], 1);
            w[4 * k + 0] = ((unsigned)(d.x & (NPB - 1)) << SRC_BITS) | (unsigned)s.x;
            w[4 * k + 1] = ((unsigned)(d.y & (NPB - 1)) << SRC_BITS) | (unsigned)s.y;
            w[4 * k + 2] = ((unsigned)(d.z & (NPB - 1)) << SRC_BITS) | (unsigned)s.z;
            w[4 * k + 3] = ((unsigned)(d.w & (NPB - 1)) << SRC_BITS) | (unsigned)s.w;
            m[4 * k + 0] = ((unsigned)b0 << 14) | (unsigned)r0;
            m[4 * k + 1] = ((unsigned)b1 << 14) | (unsigned)r1;
            m[4 * k + 2] = ((unsigned)b2 << 14) | (unsigned)r2;
            m[4 * k + 3] = ((unsigned)b3 << 14) | (unsigned)r3;
        }
    } else {
#pragma unroll
        for (int k = 0; k < 32; ++k) {
            int i = beg + tid + k * 512;
            if (i < end) {
                int d = dst[i];
                int s = src[i];
                int bkt = d >> NPB_SHIFT;
                int r = atomicAdd(&hist[bkt], 1);
                w[k] = ((unsigned)(d & (NPB - 1)) << SRC_BITS) | (unsigned)s;
                m[k] = ((unsigned)bkt << 14) | (unsigned)r;
            } else {
                m[k] = 0xFFFFFFFFu;
            }
        }
    }
    __syncthreads();

    // Phase B: scan counts -> lbase; reserve global chunks (gbase into hist)
    int v0 = hist[i0], v1 = hist[i1];
    sm[i0] = v0; sm[i1] = v1;
    __syncthreads();
    for (int off = 1; off < MAXB; off <<= 1) {
        int t0 = (i0 >= off) ? sm[i0 - off] : 0;
        int t1 = (i1 >= off) ? sm[i1 - off] : 0;
        __syncthreads();
        sm[i0] += t0; sm[i1] += t1;
        __syncthreads();
    }
    lbase[i0] = sm[i0] - v0;
    lbase[i1] = sm[i1] - v1;
    if (i0 < B) hist[i0] = v0 ? atomicAdd(&bcur[i0], v0) : 0;
    if (i1 < B) hist[i1] = v1 ? atomicAdd(&bcur[i1], v1) : 0;
    if (tid == 0) lbase[B] = cnt;
    __syncthreads();

    // Phase C: place into staging (no atomics; rank precomputed)
#pragma unroll
    for (int k = 0; k < 32; ++k) {
        if (m[k] != 0xFFFFFFFFu) {
            int bkt = (int)(m[k] >> 14);
            int r   = (int)(m[k] & 16383u);
            stg[lbase[bkt] + r] = w[k];
        }
    }
    __syncthreads();

    // Phase D: linear drain; coalesced full-line bursts per bucket chunk
    for (int j = tid; j < cnt; j += 512) {
        int lo = 0, hi = B;
        while (hi - lo > 1) {
            int mid = (lo + hi) >> 1;
            if (lbase[mid] <= j) lo = mid; else hi = mid;
        }
        packed[hist[lo] + (j - lbase[lo])] = stg[j];
    }
}

// ---------------------------------------------------------------------------
// Per-bucket fine sort, LDS-staged: one global read of packed (ranks captured
// from histogram atomics into VGPRs), atomic-free LDS scatter, linear
// coalesced csr drain. + fused degree/dinv/ptr2/xs3 production.
// ---------------------------------------------------------------------------
__global__ __launch_bounds__(512) void k_fine(const int* __restrict__ bcur,
                                              const unsigned* __restrict__ packed,
                                              int* __restrict__ csr,
                                              int2* __restrict__ ptr2,
                                              float* __restrict__ dinv,
                                              float* __restrict__ sqd,
                                              const float* __restrict__ node,
                                              float* __restrict__ xs3,   // [N,4]
                                              int N, int cap) {
    __shared__ unsigned stg[FCAP];   // ~69 KB sorted-src staging
    __shared__ int hist[NPB];
    __shared__ int exs[NPB];
    int b = blockIdx.x;
    int tid = threadIdx.x;
    int beg = b * cap;
    int cnt = min(bcur[b] - beg, FCAP);
    if (tid < NPB) hist[tid] = 0;
    __syncthreads();

    // Pass A: load bucket words into VGPRs + histogram with rank capture
    unsigned w[FK];
    int r[FK];
#pragma unroll
    for (int k = 0; k < FK; ++k) {
        int i = tid + k * 512;
        if (i < cnt) {
            w[k] = packed[beg + i];
            r[k] = atomicAdd(&hist[w[k] >> SRC_BITS], 1);
        }
    }
    __syncthreads();

    // Pass B: 256-entry scan -> exclusive segment bases; node outputs
    int hv = 0;
    if (tid < NPB) { hv = hist[tid]; exs[tid] = hv; }
    __syncthreads();
    for (int off = 1; off < NPB; off <<= 1) {
        int t = 0;
        if (tid < NPB && tid >= off) t = exs[tid - off];
        __syncthreads();
        if (tid < NPB) exs[tid] += t;
        __syncthreads();
    }
    if (tid < NPB) {
        int ex = exs[tid] - hv;  // exclusive
        int v = b * NPB + tid;
        if (v < N) {
            ptr2[v] = make_int2(beg + ex, beg + ex + hv);
            float c = (float)(hv + 1);      // +1: self-loop
            float di = rsqrtf(c);
            dinv[v] = di;
            sqd[v] = sqrtf(c);              // = 1/di, residual reconstruction
            xs3[(size_t)v * 4 + 0] = di * node[(size_t)v * 3 + 0];
            xs3[(size_t)v * 4 + 1] = di * node[(size_t)v * 3 + 1];
            xs3[(size_t)v * 4 + 2] = di * node[(size_t)v * 3 + 2];
            xs3[(size_t)v * 4 + 3] = 0.f;
        }
        exs[tid] = ex;
    }
    __syncthreads();

    // Pass C: atomic-free LDS scatter into sorted order
#pragma unroll
    for (int k = 0; k < FK; ++k) {
        int i = tid + k * 512;
        if (i < cnt) {
            int dl = (int)(w[k] >> SRC_BITS);
            stg[exs[dl] + r[k]] = w[k] & SRC_MASK;
        }
    }
    __syncthreads();

    // Pass D: linear coalesced drain to global csr
    for (int j = tid; j < cnt; j += 512)
        csr[beg + j] = (int)stg[j];
}

// ---------------------------------------------------------------------------
// Fused conv: 4 nodes per wave (16-lane segments), int2 segment bounds.
// MODE 0: first conv (F=3, fp32 gathers). MODE 1: mid. MODE 2: final -> out.
// ---------------------------------------------------------------------------
template <int MODE>
__global__ __launch_bounds__(512) void k_conv(const int2* __restrict__ ptr2,
                                              const int* __restrict__ csr,
                                              const float* __restrict__ dinv,
                                              const float* __restrict__ sqd,
                                              const float* __restrict__ xs,   // fp32: MODE0 [N,4], else [N,8]
                                              const __half* __restrict__ xsh, // fp16 [N,8] (MODE1/2)
                                              const float* __restrict__ W,
                                              const float* __restrict__ b,
                                              const float* __restrict__ gamma,
                                              const float* __restrict__ beta,
                                              const float* __restrict__ Wfc,
                                              const float* __restrict__ bfc,
                                              float* __restrict__ xsout,      // fp32 [N,8]
                                              __half* __restrict__ xhout,     // fp16 [N,8]
                                              float* __restrict__ outfc,      // [N,3]
                                              int N) {
    constexpr int F = (MODE == 0) ? 3 : 6;
    int wave = threadIdx.x >> 6;
    int lane = threadIdx.x & 63;
    int sub  = lane >> 4;        // 0..3: which node in this wave
    int li   = lane & 15;        // lane within 16-lane segment
    int v = (blockIdx.x * 8 + wave) * 4 + sub;
    bool valid = v < N;
    int beg = 0, end = 0;
    if (valid) { int2 p = ptr2[v]; beg = p.x; end = p.y; }

    float a0 = 0.f, a1 = 0.f, a2 = 0.f, a3 = 0.f, a4 = 0.f, a5 = 0.f;
    if constexpr (F == 3) {
        const float4* x4 = (const float4*)xs;
        for (int i = beg + li; i < end; i += 16) {
            float4 p = x4[csr[i]];
            a0 += p.x; a1 += p.y; a2 += p.z;
        }
        if (valid && li == 0) { float4 p = x4[v]; a0 += p.x; a1 += p.y; a2 += p.z; }
    } else {
        const float4* xh4 = (const float4*)xsh;  // 8 halves = 16B
        for (int i = beg + li; i < end; i += 16) {
            float4 raw = xh4[csr[i]];
            const __half2* h2 = (const __half2*)&raw;
            float2 p0 = __half22float2(h2[0]);
            float2 p1 = __half22float2(h2[1]);
            float2 p2 = __half22float2(h2[2]);
            a0 += p0.x; a1 += p0.y; a2 += p1.x; a3 += p1.y; a4 += p2.x; a5 += p2.y;
        }
        if (valid && li == 0) {  // self-loop, fp32
            const float* r = xs + (size_t)v * 8;
            float4 p = *(const float4*)r;
            float2 q = *(const float2*)(r + 4);
            a0 += p.x; a1 += p.y; a2 += p.z; a3 += p.w; a4 += q.x; a5 += q.y;
        }
    }
#pragma unroll
    for (int off = 8; off >= 1; off >>= 1) {
        a0 += __shfl_down(a0, off);
        a1 += __shfl_down(a1, off);
        a2 += __shfl_down(a2, off);
        if constexpr (F == 6) {
            a3 += __shfl_down(a3, off);
            a4 += __shfl_down(a4, off);
            a5 += __shfl_down(a5, off);
        }
    }
    if (li != 0 || !valid) return;

    float di = dinv[v];
    float t[F];
    t[0] = di * a0; t[1] = di * a1; t[2] = di * a2;
    if constexpr (F == 6) { t[3] = di * a3; t[4] = di * a4; t[5] = di * a5; }

    float y[6];
#pragma unroll
    for (int j = 0; j < 6; ++j) {
        float acc = b[j];
#pragma unroll
        for (int k = 0; k < F; ++k) acc += t[k] * W[k * 6 + j];
        y[j] = acc;
    }

    if constexpr (MODE == 0) {
        float* o = xsout + (size_t)v * 8;
        *(float4*)o = make_float4(di * y[0], di * y[1], di * y[2], di * y[3]);
        *(float2*)(o + 4) = make_float2(di * y[4], di * y[5]);
        __half2* oh = (__half2*)(xhout + (size_t)v * 8);
        oh[0] = __floats2half2_rn(di * y[0], di * y[1]);
        oh[1] = __floats2half2_rn(di * y[2], di * y[3]);
        oh[2] = __floats2half2_rn(di * y[4], di * y[5]);
        oh[3] = __floats2half2_rn(0.f, 0.f);
    } else {
        float mu = 0.f;
#pragma unroll
        for (int j = 0; j < 6; ++j) mu += y[j];
        mu *= (1.f / 6.f);
        float var = 0.f;
#pragma unroll
        for (int j = 0; j < 6; ++j) { float dl = y[j] - mu; var += dl * dl; }
        var *= (1.f / 6.f);
        float rs = rsqrtf(var + EPSLN);
        float sq = sqd[v];
        const float* xr = xs + (size_t)v * 8;   // residual = xs * sqrt(deg+1)
        float r[6];
#pragma unroll
        for (int j = 0; j < 6; ++j) {
            float z = (y[j] - mu) * rs * gamma[j] + beta[j] + xr[j] * sq;
            r[j] = z > 0.f ? z : 0.f;
        }
        if constexpr (MODE == 1) {
            float* o = xsout + (size_t)v * 8;
            *(float4*)o = make_float4(di * r[0], di * r[1], di * r[2], di * r[3]);
            *(float2*)(o + 4) = make_float2(di * r[4], di * r[5]);
            __half2* oh = (__half2*)(xhout + (size_t)v * 8);
            oh[0] = __floats2half2_rn(di * r[0], di * r[1]);
            oh[1] = __floats2half2_rn(di * r[2], di * r[3]);
            oh[2] = __floats2half2_rn(di * r[4], di * r[5]);
            oh[3] = __floats2half2_rn(0.f, 0.f);
        } else {
#pragma unroll
            for (int j = 0; j < 3; ++j) {
                float acc = bfc[j];
#pragma unroll
                for (int k = 0; k < 6; ++k) acc += r[k] * Wfc[k * 3 + j];
                outfc[(size_t)v * 3 + j] = acc;
            }
        }
    }
}

// ---------------------------------------------------------------------------
extern "C" void kernel_launch(void* const* d_in, const int* in_sizes, int n_in,
                              void* d_out, int out_size, void* d_ws, size_t ws_size,
                              hipStream_t stream) {
    const float* node  = (const float*)d_in[0];
    const int*   edges = (const int*)d_in[1];
    const float* W1    = (const float*)d_in[2];
    const float* b1    = (const float*)d_in[3];
    const float* Wl    = (const float*)d_in[4];
    const float* bl    = (const float*)d_in[5];
    const float* gamma = (const float*)d_in[6];
    const float* beta  = (const float*)d_in[7];
    const float* Wfc   = (const float*)d_in[8];
    const float* bfc   = (const float*)d_in[9];
    float* out = (float*)d_out;

    const int N     = in_sizes[0] / 3;
    const int E     = in_sizes[1] / 2;
    const int STEPS = in_sizes[4] / 36;
    const int* src = edges;
    const int* dst = edges + E;
    const int B = (N + NPB - 1) / NPB;   // 782 for N=200000

    // Fixed bucket capacity: mean + ~8 sigma, 256-aligned, clamped to LDS cap
    const int mean = E / B;
    int CAP = (mean + 8 * (int)(sqrt((double)mean) + 1) + 255) & ~255;
    if (CAP > FCAP) CAP = FCAP;

    char* ws = (char*)d_ws;
    size_t off = 0;
    auto alloc = [&](size_t bytes) -> void* {
        void* p = ws + off;
        off += (bytes + 255) & ~(size_t)255;
        return p;
    };
    int*      bcur   = (int*)alloc((size_t)B * sizeof(int));
    int2*     ptr2   = (int2*)alloc((size_t)N * sizeof(int2));
    float*    dinv   = (float*)alloc((size_t)N * sizeof(float));
    float*    sqd    = (float*)alloc((size_t)N * sizeof(float));
    unsigned* packed = (unsigned*)alloc((size_t)B * CAP * sizeof(unsigned));
    int*      csr    = (int*)alloc((size_t)B * CAP * sizeof(int));
    float*    xs3    = (float*)alloc((size_t)N * 4 * sizeof(float));
    float*    xsa    = (float*)alloc((size_t)N * 8 * sizeof(float));
    float*    xsb    = (float*)alloc((size_t)N * 8 * sizeof(float));
    __half*   xha    = (__half*)alloc((size_t)N * 8 * sizeof(__half));
    __half*   xhb    = (__half*)alloc((size_t)N * 8 * sizeof(__half));
    (void)ws_size;

    const int gS = (E + TILE - 1) / TILE;   // 782
    const int gC = (N + 31) / 32;           // 4 nodes/wave, 8 waves/block

    k_init<<<(B + 511) / 512, 512, 0, stream>>>(bcur, B, CAP);
    k_scatter<<<gS, 512, 0, stream>>>(src, dst, bcur, packed, E, B);
    k_fine<<<B, 512, 0, stream>>>(bcur, packed, csr, ptr2, dinv, sqd, node, xs3, N, CAP);

    // Conv 1 (F=3): xsa/xha = dinv * ((A_hat @ node) @ W1 + b1)
    k_conv<0><<<gC, 512, 0, stream>>>(ptr2, csr, dinv, sqd, xs3, nullptr, W1, b1,
                                      nullptr, nullptr, nullptr, nullptr,
                                      xsa, xha, nullptr, N);

    float* xscur = xsa;   __half* xhcur = xha;
    float* xsnxt = xsb;   __half* xhnxt = xhb;
    for (int i = 0; i < STEPS; ++i) {
        const float* W  = Wl + (size_t)i * 36;
        const float* bb = bl + (size_t)i * 6;
        const float* g  = gamma + (size_t)i * 6;
        const float* be = beta + (size_t)i * 6;
        if (i == STEPS - 1) {
            k_conv<2><<<gC, 512, 0, stream>>>(ptr2, csr, dinv, sqd, xscur, xhcur, W, bb,
                                              g, be, Wfc, bfc, nullptr, nullptr, out, N);
        } else {
            k_conv<1><<<gC, 512, 0, stream>>>(ptr2, csr, dinv, sqd, xscur, xhcur, W, bb,
                                              g, be, nullptr, nullptr, xsnxt, xhnxt, nullptr, N);
        }
        float* t1 = xscur; xscur = xsnxt; xsnxt = t1;
        __half* t2 = xhcur; xhcur = xhnxt; xhnxt = t2;
    }
}

// Round 11
// 612.222 us; speedup vs baseline: 4.4211x; 1.0486x over previous
//
#include <hip/hip_runtime.h>
#include <hip/hip_fp16.h>
#include <cstdint>

#define EPSLN 1e-5f
#define NPB 256          // nodes per bucket (power of 2)
#define NPB_SHIFT 8
#define MAXB 1024        // max buckets (N <= 262144)
#define TILE 16384       // edges per sort tile (LDS staging = 64KB)
#define SRC_BITS 18      // src id fits 18 bits (N <= 262144)
#define SRC_MASK 0x3FFFF
#define FCAP 17664       // k_fine LDS staging words; >= CAP (mean+8sigma, 256-aligned)
#define FK 35            // FCAP / 512 rounded up

// ---------------------------------------------------------------------------
// Init per-bucket global cursors to fixed-capacity bases: bcur[b] = b*CAP
// ---------------------------------------------------------------------------
__global__ __launch_bounds__(512) void k_init(int* __restrict__ bcur, int B, int cap) {
    int b = blockIdx.x * 512 + threadIdx.x;
    if (b < B) bcur[b] = b * cap;
}

// ---------------------------------------------------------------------------
// Single-pass rank-based scatter: one LDS atomic per edge yields (bucket,
// rank); placement atomic-free; per-wave bucket-range drain (no search).
// ---------------------------------------------------------------------------
__global__ __launch_bounds__(512) void k_scatter(const int* __restrict__ src,
                                                 const int* __restrict__ dst,
                                                 int* __restrict__ bcur,
                                                 unsigned* __restrict__ packed,
                                                 int E, int B) {
    __shared__ unsigned stg[TILE];     // 64 KB staging
    __shared__ int hist[MAXB];         // counts, then reused as gbase
    __shared__ int lbase[MAXB + 1];    // exclusive scan (local segment bases)
    __shared__ int sm[MAXB];           // scan workspace
    int tid = threadIdx.x;
    int i0 = tid, i1 = tid + 512;
    hist[i0] = 0; hist[i1] = 0;
    __syncthreads();

    int beg = blockIdx.x * TILE;
    int end = min(beg + TILE, E);
    int cnt = end - beg;

    unsigned w[32];   // packed payload words
    unsigned m[32];   // meta: (bkt<<14)|rank, 0xFFFFFFFF = invalid

    // Phase A: load + histogram + rank (single pass over src/dst)
    if (cnt == TILE && ((E & 3) == 0)) {
        const int4* d4 = (const int4*)(dst + beg);
        const int4* s4 = (const int4*)(src + beg);
#pragma unroll
        for (int k = 0; k < 8; ++k) {
            int4 d = d4[tid + k * 512];
            int4 s = s4[tid + k * 512];
            int b0 = d.x >> NPB_SHIFT, b1 = d.y >> NPB_SHIFT;
            int b2 = d.z >> NPB_SHIFT, b3 = d.w >> NPB_SHIFT;
            int r0 = atomicAdd(&hist[b0], 1);
            int r1 = atomicAdd(&hist[b1], 1);
            int r2 = atomicAdd(&hist[b2], 1);
            int r3 = atomicAdd(&hist[b3], 1);
            w[4 * k + 0] = ((unsigned)(d.x & (NPB - 1)) << SRC_BITS) | (unsigned)s.x;
            w[4 * k + 1] = ((unsigned)(d.y & (NPB - 1)) << SRC_BITS) | (unsigned)s.y;
            w[4 * k + 2] = ((unsigned)(d.z & (NPB - 1)) << SRC_BITS) | (unsigned)s.z;
            w[4 * k + 3] = ((unsigned)(d.w & (NPB - 1)) << SRC_BITS) | (unsigned)s.w;
            m[4 * k + 0] = ((unsigned)b0 << 14) | (unsigned)r0;
            m[4 * k + 1] = ((unsigned)b1 << 14) | (unsigned)r1;
            m[4 * k + 2] = ((unsigned)b2 << 14) | (unsigned)r2;
            m[4 * k + 3] = ((unsigned)b3 << 14) | (unsigned)r3;
        }
    } else {
#pragma unroll
        for (int k = 0; k < 32; ++k) {
            int i = beg + tid + k * 512;
            if (i < end) {
                int d = dst[i];
                int s = src[i];
                int bkt = d >> NPB_SHIFT;
                int r = atomicAdd(&hist[bkt], 1);
                w[k] = ((unsigned)(d & (NPB - 1)) << SRC_BITS) | (unsigned)s;
                m[k] = ((unsigned)bkt << 14) | (unsigned)r;
            } else {
                m[k] = 0xFFFFFFFFu;
            }
        }
    }
    __syncthreads();

    // Phase B: scan counts -> lbase; reserve global chunks (gbase into hist)
    int v0 = hist[i0], v1 = hist[i1];
    sm[i0] = v0; sm[i1] = v1;
    __syncthreads();
    for (int off = 1; off < MAXB; off <<= 1) {
        int t0 = (i0 >= off) ? sm[i0 - off] : 0;
        int t1 = (i1 >= off) ? sm[i1 - off] : 0;
        __syncthreads();
        sm[i0] += t0; sm[i1] += t1;
        __syncthreads();
    }
    lbase[i0] = sm[i0] - v0;
    lbase[i1] = sm[i1] - v1;
    if (i0 < B) hist[i0] = v0 ? atomicAdd(&bcur[i0], v0) : 0;
    if (i1 < B) hist[i1] = v1 ? atomicAdd(&bcur[i1], v1) : 0;
    if (tid == 0) lbase[B] = cnt;
    __syncthreads();

    // Phase C: place into staging (no atomics; rank precomputed)
#pragma unroll
    for (int k = 0; k < 32; ++k) {
        if (m[k] != 0xFFFFFFFFu) {
            int bkt = (int)(m[k] >> 14);
            int r   = (int)(m[k] & 16383u);
            stg[lbase[bkt] + r] = w[k];
        }
    }
    __syncthreads();

    // Phase D: per-wave bucket-range drain (wave-uniform LDS broadcasts,
    // coalesced chunk copy; no per-word search)
    int wv = tid >> 6;
    int ln = tid & 63;
    for (int b = wv; b < B; b += 8) {
        int lb = lbase[b];
        int le = lbase[b + 1];
        int gb = hist[b];
        for (int j = lb + ln; j < le; j += 64)
            packed[gb + (j - lb)] = stg[j];
    }
}

// ---------------------------------------------------------------------------
// Per-bucket fine sort, LDS-staged: one global read of packed (ranks captured
// from histogram atomics into VGPRs), atomic-free LDS scatter, linear
// coalesced csr drain. + fused degree/dinv/ptr2/xs3 production.
// ---------------------------------------------------------------------------
__global__ __launch_bounds__(512) void k_fine(const int* __restrict__ bcur,
                                              const unsigned* __restrict__ packed,
                                              int* __restrict__ csr,
                                              int2* __restrict__ ptr2,
                                              float* __restrict__ dinv,
                                              float* __restrict__ sqd,
                                              const float* __restrict__ node,
                                              float* __restrict__ xs3,   // [N,4]
                                              int N, int cap) {
    __shared__ unsigned stg[FCAP];   // ~69 KB sorted-src staging
    __shared__ int hist[NPB];
    __shared__ int exs[NPB];
    int b = blockIdx.x;
    int tid = threadIdx.x;
    int beg = b * cap;
    int cnt = min(bcur[b] - beg, FCAP);
    if (tid < NPB) hist[tid] = 0;
    __syncthreads();

    // Pass A: load bucket words into VGPRs + histogram with rank capture
    unsigned w[FK];
    int r[FK];
#pragma unroll
    for (int k = 0; k < FK; ++k) {
        int i = tid + k * 512;
        if (i < cnt) {
            w[k] = packed[beg + i];
            r[k] = atomicAdd(&hist[w[k] >> SRC_BITS], 1);
        }
    }
    __syncthreads();

    // Pass B: 256-entry scan -> exclusive segment bases; node outputs
    int hv = 0;
    if (tid < NPB) { hv = hist[tid]; exs[tid] = hv; }
    __syncthreads();
    for (int off = 1; off < NPB; off <<= 1) {
        int t = 0;
        if (tid < NPB && tid >= off) t = exs[tid - off];
        __syncthreads();
        if (tid < NPB) exs[tid] += t;
        __syncthreads();
    }
    if (tid < NPB) {
        int ex = exs[tid] - hv;  // exclusive
        int v = b * NPB + tid;
        if (v < N) {
            ptr2[v] = make_int2(beg + ex, beg + ex + hv);
            float c = (float)(hv + 1);      // +1: self-loop
            float di = rsqrtf(c);
            dinv[v] = di;
            sqd[v] = sqrtf(c);              // = 1/di, residual reconstruction
            xs3[(size_t)v * 4 + 0] = di * node[(size_t)v * 3 + 0];
            xs3[(size_t)v * 4 + 1] = di * node[(size_t)v * 3 + 1];
            xs3[(size_t)v * 4 + 2] = di * node[(size_t)v * 3 + 2];
            xs3[(size_t)v * 4 + 3] = 0.f;
        }
        exs[tid] = ex;
    }
    __syncthreads();

    // Pass C: atomic-free LDS scatter into sorted order
#pragma unroll
    for (int k = 0; k < FK; ++k) {
        int i = tid + k * 512;
        if (i < cnt) {
            int dl = (int)(w[k] >> SRC_BITS);
            stg[exs[dl] + r[k]] = w[k] & SRC_MASK;
        }
    }
    __syncthreads();

    // Pass D: linear coalesced drain to global csr
    for (int j = tid; j < cnt; j += 512)
        csr[beg + j] = (int)stg[j];
}

// ---------------------------------------------------------------------------
// Fused conv: 4 nodes per wave (16-lane segments), int2 segment bounds,
// software-pipelined csr prefetch (csr load for iter k+1 overlaps gather k).
// MODE 0: first conv (F=3, fp32 gathers). MODE 1: mid. MODE 2: final -> out.
// ---------------------------------------------------------------------------
template <int MODE>
__global__ __launch_bounds__(512) void k_conv(const int2* __restrict__ ptr2,
                                              const int* __restrict__ csr,
                                              const float* __restrict__ dinv,
                                              const float* __restrict__ sqd,
                                              const float* __restrict__ xs,   // fp32: MODE0 [N,4], else [N,8]
                                              const __half* __restrict__ xsh, // fp16 [N,8] (MODE1/2)
                                              const float* __restrict__ W,
                                              const float* __restrict__ b,
                                              const float* __restrict__ gamma,
                                              const float* __restrict__ beta,
                                              const float* __restrict__ Wfc,
                                              const float* __restrict__ bfc,
                                              float* __restrict__ xsout,      // fp32 [N,8]
                                              __half* __restrict__ xhout,     // fp16 [N,8]
                                              float* __restrict__ outfc,      // [N,3]
                                              int N) {
    constexpr int F = (MODE == 0) ? 3 : 6;
    int wave = threadIdx.x >> 6;
    int lane = threadIdx.x & 63;
    int sub  = lane >> 4;        // 0..3: which node in this wave
    int li   = lane & 15;        // lane within 16-lane segment
    int v = (blockIdx.x * 8 + wave) * 4 + sub;
    bool valid = v < N;
    int beg = 0, end = 0;
    if (valid) { int2 p = ptr2[v]; beg = p.x; end = p.y; }

    float a0 = 0.f, a1 = 0.f, a2 = 0.f, a3 = 0.f, a4 = 0.f, a5 = 0.f;
    if constexpr (F == 3) {
        const float4* x4 = (const float4*)xs;
        // self-loop issued before the loop (independent load)
        if (valid && li == 0) { float4 p = x4[v]; a0 += p.x; a1 += p.y; a2 += p.z; }
        int i = beg + li;
        int idx = (i < end) ? csr[i] : 0;
        while (i < end) {
            int inext = i + 16;
            int idxn = (inext < end) ? csr[inext] : 0;   // prefetch next
            float4 p = x4[idx];
            a0 += p.x; a1 += p.y; a2 += p.z;
            i = inext; idx = idxn;
        }
    } else {
        const float4* xh4 = (const float4*)xsh;  // 8 halves = 16B
        if (valid && li == 0) {  // self-loop, fp32, issued early
            const float* r = xs + (size_t)v * 8;
            float4 p = *(const float4*)r;
            float2 q = *(const float2*)(r + 4);
            a0 += p.x; a1 += p.y; a2 += p.z; a3 += p.w; a4 += q.x; a5 += q.y;
        }
        int i = beg + li;
        int idx = (i < end) ? csr[i] : 0;
        while (i < end) {
            int inext = i + 16;
            int idxn = (inext < end) ? csr[inext] : 0;   // prefetch next
            float4 raw = xh4[idx];
            const __half2* h2 = (const __half2*)&raw;
            float2 p0 = __half22float2(h2[0]);
            float2 p1 = __half22float2(h2[1]);
            float2 p2 = __half22float2(h2[2]);
            a0 += p0.x; a1 += p0.y; a2 += p1.x; a3 += p1.y; a4 += p2.x; a5 += p2.y;
            i = inext; idx = idxn;
        }
    }
#pragma unroll
    for (int off = 8; off >= 1; off >>= 1) {
        a0 += __shfl_down(a0, off);
        a1 += __shfl_down(a1, off);
        a2 += __shfl_down(a2, off);
        if constexpr (F == 6) {
            a3 += __shfl_down(a3, off);
            a4 += __shfl_down(a4, off);
            a5 += __shfl_down(a5, off);
        }
    }
    if (li != 0 || !valid) return;

    float di = dinv[v];
    float t[F];
    t[0] = di * a0; t[1] = di * a1; t[2] = di * a2;
    if constexpr (F == 6) { t[3] = di * a3; t[4] = di * a4; t[5] = di * a5; }

    float y[6];
#pragma unroll
    for (int j = 0; j < 6; ++j) {
        float acc = b[j];
#pragma unroll
        for (int k = 0; k < F; ++k) acc += t[k] * W[k * 6 + j];
        y[j] = acc;
    }

    if constexpr (MODE == 0) {
        float* o = xsout + (size_t)v * 8;
        *(float4*)o = make_float4(di * y[0], di * y[1], di * y[2], di * y[3]);
        *(float2*)(o + 4) = make_float2(di * y[4], di * y[5]);
        __half2* oh = (__half2*)(xhout + (size_t)v * 8);
        oh[0] = __floats2half2_rn(di * y[0], di * y[1]);
        oh[1] = __floats2half2_rn(di * y[2], di * y[3]);
        oh[2] = __floats2half2_rn(di * y[4], di * y[5]);
        oh[3] = __floats2half2_rn(0.f, 0.f);
    } else {
        float mu = 0.f;
#pragma unroll
        for (int j = 0; j < 6; ++j) mu += y[j];
        mu *= (1.f / 6.f);
        float var = 0.f;
#pragma unroll
        for (int j = 0; j < 6; ++j) { float dl = y[j] - mu; var += dl * dl; }
        var *= (1.f / 6.f);
        float rs = rsqrtf(var + EPSLN);
        float sq = sqd[v];
        const float* xr = xs + (size_t)v * 8;   // residual = xs * sqrt(deg+1)
        float r[6];
#pragma unroll
        for (int j = 0; j < 6; ++j) {
            float z = (y[j] - mu) * rs * gamma[j] + beta[j] + xr[j] * sq;
            r[j] = z > 0.f ? z : 0.f;
        }
        if constexpr (MODE == 1) {
            float* o = xsout + (size_t)v * 8;
            *(float4*)o = make_float4(di * r[0], di * r[1], di * r[2], di * r[3]);
            *(float2*)(o + 4) = make_float2(di * r[4], di * r[5]);
            __half2* oh = (__half2*)(xhout + (size_t)v * 8);
            oh[0] = __floats2half2_rn(di * r[0], di * r[1]);
            oh[1] = __floats2half2_rn(di * r[2], di * r[3]);
            oh[2] = __floats2half2_rn(di * r[4], di * r[5]);
            oh[3] = __floats2half2_rn(0.f, 0.f);
        } else {
#pragma unroll
            for (int j = 0; j < 3; ++j) {
                float acc = bfc[j];
#pragma unroll
                for (int k = 0; k < 6; ++k) acc += r[k] * Wfc[k * 3 + j];
                outfc[(size_t)v * 3 + j] = acc;
            }
        }
    }
}

// ---------------------------------------------------------------------------
extern "C" void kernel_launch(void* const* d_in, const int* in_sizes, int n_in,
                              void* d_out, int out_size, void* d_ws, size_t ws_size,
                              hipStream_t stream) {
    const float* node  = (const float*)d_in[0];
    const int*   edges = (const int*)d_in[1];
    const float* W1    = (const float*)d_in[2];
    const float* b1    = (const float*)d_in[3];
    const float* Wl    = (const float*)d_in[4];
    const float* bl    = (const float*)d_in[5];
    const float* gamma = (const float*)d_in[6];
    const float* beta  = (const float*)d_in[7];
    const float* Wfc   = (const float*)d_in[8];
    const float* bfc   = (const float*)d_in[9];
    float* out = (float*)d_out;

    const int N     = in_sizes[0] / 3;
    const int E     = in_sizes[1] / 2;
    const int STEPS = in_sizes[4] / 36;
    const int* src = edges;
    const int* dst = edges + E;
    const int B = (N + NPB - 1) / NPB;   // 782 for N=200000

    // Fixed bucket capacity: mean + ~8 sigma, 256-aligned, clamped to LDS cap
    const int mean = E / B;
    int CAP = (mean + 8 * (int)(sqrt((double)mean) + 1) + 255) & ~255;
    if (CAP > FCAP) CAP = FCAP;

    char* ws = (char*)d_ws;
    size_t off = 0;
    auto alloc = [&](size_t bytes) -> void* {
        void* p = ws + off;
        off += (bytes + 255) & ~(size_t)255;
        return p;
    };
    int*      bcur   = (int*)alloc((size_t)B * sizeof(int));
    int2*     ptr2   = (int2*)alloc((size_t)N * sizeof(int2));
    float*    dinv   = (float*)alloc((size_t)N * sizeof(float));
    float*    sqd    = (float*)alloc((size_t)N * sizeof(float));
    unsigned* packed = (unsigned*)alloc((size_t)B * CAP * sizeof(unsigned));
    int*      csr    = (int*)alloc((size_t)B * CAP * sizeof(int));
    float*    xs3    = (float*)alloc((size_t)N * 4 * sizeof(float));
    float*    xsa    = (float*)alloc((size_t)N * 8 * sizeof(float));
    float*    xsb    = (float*)alloc((size_t)N * 8 * sizeof(float));
    __half*   xha    = (__half*)alloc((size_t)N * 8 * sizeof(__half));
    __half*   xhb    = (__half*)alloc((size_t)N * 8 * sizeof(__half));
    (void)ws_size;

    const int gS = (E + TILE - 1) / TILE;   // 782
    const int gC = (N + 31) / 32;           // 4 nodes/wave, 8 waves/block

    k_init<<<(B + 511) / 512, 512, 0, stream>>>(bcur, B, CAP);
    k_scatter<<<gS, 512, 0, stream>>>(src, dst, bcur, packed, E, B);
    k_fine<<<B, 512, 0, stream>>>(bcur, packed, csr, ptr2, dinv, sqd, node, xs3, N, CAP);

    // Conv 1 (F=3): xsa/xha = dinv * ((A_hat @ node) @ W1 + b1)
    k_conv<0><<<gC, 512, 0, stream>>>(ptr2, csr, dinv, sqd, xs3, nullptr, W1, b1,
                                      nullptr, nullptr, nullptr, nullptr,
                                      xsa, xha, nullptr, N);

    float* xscur = xsa;   __half* xhcur = xha;
    float* xsnxt = xsb;   __half* xhnxt = xhb;
    for (int i = 0; i < STEPS; ++i) {
        const float* W  = Wl + (size_t)i * 36;
        const float* bb = bl + (size_t)i * 6;
        const float* g  = gamma + (size_t)i * 6;
        const float* be = beta + (size_t)i * 6;
        if (i == STEPS - 1) {
            k_conv<2><<<gC, 512, 0, stream>>>(ptr2, csr, dinv, sqd, xscur, xhcur, W, bb,
                                              g, be, Wfc, bfc, nullptr, nullptr, out, N);
        } else {
            k_conv<1><<<gC, 512, 0, stream>>>(ptr2, csr, dinv, sqd, xscur, xhcur, W, bb,
                                              g, be, nullptr, nullptr, xsnxt, xhnxt, nullptr, N);
        }
        float* t1 = xscur; xscur = xsnxt; xsnxt = t1;
        __half* t2 = xhcur; xhcur = xhnxt; xhnxt = t2;
    }
}